// Round 3
// baseline (59426.422 us; speedup 1.0000x reference)
//
#include <hip/hip_runtime.h>

// ---------------- problem constants ----------------
#define NN      16384      // total nodes
#define TSTEPS  32
#define SG      256        // graphs
#define NE      262144
#define NPANEL  24         // 22 panels for xl@Wih (21x384 + 128) + 2 for lh@Whh (384+128)
#define GSTRIDE 524288u    // 256*2048 floats per panel partial

// ---------------- workspace layout (float offsets) ----------------
#define OFF_ENC_MEM   0u
#define OFF_ENC_SPK   2097152u
#define OFF_C1_MEM    4194304u
#define OFF_C1_SPK    6291456u     // == xl [256][8192]
#define OFF_LH        8388608u
#define OFF_LC        8519680u
#define OFF_H1_MEM    8650752u
#define OFF_H1_SPK    8716288u
#define OFF_H2_MEM    8781824u
#define OFF_H2_SPK    8782848u
#define OFF_H2_SUM    8783872u
#define ZERO_FLOATS   8784896u     // everything below here zeroed each launch
#define OFF_BASES     8784896u
#define OFF_COMB      9833472u
#define OFF_GATES     10357760u    // 256 x 2048
#define OFF_PART      10882048u    // 24 x 256 x 2048 panel partials
#define OFF_DINV      23464960u
#define OFF_COLW      23481344u
#define FLOAT_END     23743488u
// int region (offsets from ibase)
#define IOFF_DEG      0
#define IOFF_FILL     16384
#define IOFF_ROWPTR   32768
#define IOFF_EID      49153
#define IOFF_COL      311297
#define INT_COUNT     573441

// ---------------- graph preprocessing ----------------
__global__ void k_deg(const int* __restrict__ ei, int* __restrict__ deg) {
  int e = blockIdx.x * 256 + threadIdx.x;
  if (e < NE) atomicAdd(&deg[ei[NE + e]], 1);
}

__global__ void k_dinv(const int* __restrict__ deg, float* __restrict__ dinv) {
  int n = blockIdx.x * 256 + threadIdx.x;
  if (n < NN) dinv[n] = __fdiv_rn(1.0f, __fsqrt_rn((float)(deg[n] + 1)));  // +1 self-loop
}

__global__ void k_scan(const int* __restrict__ deg, int* __restrict__ rowp) {
  __shared__ int sdata[1024];
  int tid = threadIdx.x;
  int base = tid * 16;
  int loc[16];
  int sum = 0;
  #pragma unroll
  for (int i = 0; i < 16; ++i) { loc[i] = sum; sum += deg[base + i]; }
  sdata[tid] = sum;
  __syncthreads();
  for (int off = 1; off < 1024; off <<= 1) {
    int v = 0;
    if (tid >= off) v = sdata[tid - off];
    __syncthreads();
    sdata[tid] += v;
    __syncthreads();
  }
  int excl = (tid == 0) ? 0 : sdata[tid - 1];
  #pragma unroll
  for (int i = 0; i < 16; ++i) rowp[base + i] = excl + loc[i];
  if (tid == 1023) rowp[NN] = sdata[1023];
}

__global__ void k_scatter(const int* __restrict__ ei, const int* __restrict__ rowp,
                          int* __restrict__ fill, int* __restrict__ eid) {
  int e = blockIdx.x * 256 + threadIdx.x;
  if (e >= NE) return;
  int d = ei[NE + e];
  int pos = rowp[d] + atomicAdd(&fill[d], 1);
  eid[pos] = e;
}

// sort each adjacency list by EDGE ID (unique keys) -> summation order == scatter-add order
__global__ void k_sortadj(const int* __restrict__ rowp, int* __restrict__ eid,
                          const int* __restrict__ ei, const float* __restrict__ dinv,
                          int* __restrict__ col, float* __restrict__ colw) {
  int d = blockIdx.x * 256 + threadIdx.x;
  if (d >= NN) return;
  int r0 = rowp[d], r1 = rowp[d + 1];
  for (int i = r0 + 1; i < r1; ++i) {
    int key = eid[i];
    int j = i - 1;
    while (j >= r0 && eid[j] > key) { eid[j + 1] = eid[j]; --j; }
    eid[j + 1] = key;
  }
  for (int i = r0; i < r1; ++i) {
    int s = ei[eid[i]];
    col[i] = s;
    colw[i] = dinv[s];
  }
}

// ---------------- per-timestep kernels ----------------
// enc LIF (2 nodes/block; x staged through LDS to kill strided scalar loads)
__global__ __launch_bounds__(256) void k_enc(
    const float* __restrict__ x, const float* __restrict__ encW, const float* __restrict__ encB,
    float* __restrict__ enc_mem, float* __restrict__ enc_spk, int t) {
  __shared__ float xs[2][8];
  int tid = threadIdx.x;
  int nb = blockIdx.x * 2;
  if (tid < 16)
    xs[tid >> 3][tid & 7] = x[(size_t)(nb + (tid >> 3)) * 256 + (size_t)(tid & 7) * 32 + t];
  __syncthreads();
  int nl = tid >> 7, j = tid & 127;
  int idx = (nb + nl) * 128 + j;
  float dot = 0.f;
  #pragma unroll
  for (int c = 0; c < 8; ++c) dot = __fmaf_rn(xs[nl][c], encW[c * 128 + j], dot);
  float m = enc_mem[idx], s = enc_spk[idx];
  float nm = __fadd_rn(__fadd_rn(__fmul_rn(__fmul_rn(m, 0.2f), __fsub_rn(1.f, s)), dot), encB[j]);
  enc_mem[idx] = nm;
  enc_spk[idx] = nm > 0.5f ? 1.f : 0.f;
}

// bases = spk @ bases_W + b ; comb = spk @ comb_W + b
__global__ __launch_bounds__(256) void k_bases_comb(
    const float* __restrict__ enc_spk,
    const float* __restrict__ basesW, const float* __restrict__ basesB,
    const float* __restrict__ combW, const float* __restrict__ combB,
    float* __restrict__ bases, float* __restrict__ comb) {
  __shared__ float sp[64 * 129];   // [node][j], pad 129 -> (n+j)%32 banks
  __shared__ float ob[64 * 65];    // bases out [node][ch], pad 65
  __shared__ float oc[64 * 33];    // comb out [node][ch], pad 33
  const int tid = threadIdx.x;
  const int nb = blockIdx.x * 64;
  #pragma unroll 4
  for (int k = 0; k < 32; ++k) {
    int idx = k * 256 + tid;
    int n = idx >> 7, j = idx & 127;
    sp[n * 129 + j] = enc_spk[(size_t)nb * 128 + idx];
  }
  __syncthreads();
  const int lane = tid & 63;
  const int w = tid >> 6;
  const float* spn = sp + lane * 129;
  if (w < 2) {
    const int ch0 = w * 32;
    const float* Wp = basesW + ch0;
    float acc[32];
    #pragma unroll
    for (int c = 0; c < 32; ++c) acc[c] = 0.f;
    for (int j = 0; j < 128; ++j) {
      const float s = spn[j];
      const float* wr = Wp + j * 64;     // lane-invariant -> scalar loads
      #pragma unroll
      for (int c = 0; c < 32; ++c) acc[c] = __fmaf_rn(s, wr[c], acc[c]);
    }
    #pragma unroll
    for (int c = 0; c < 32; ++c) ob[lane * 65 + ch0 + c] = acc[c];
  } else {
    const int ch0 = (w - 2) * 16;
    const float* Wp = combW + ch0;
    float acc[16];
    #pragma unroll
    for (int c = 0; c < 16; ++c) acc[c] = 0.f;
    for (int j = 0; j < 128; ++j) {
      const float s = spn[j];
      const float* wr = Wp + j * 32;
      #pragma unroll
      for (int c = 0; c < 16; ++c) acc[c] = __fmaf_rn(s, wr[c], acc[c]);
    }
    #pragma unroll
    for (int c = 0; c < 16; ++c) oc[lane * 33 + ch0 + c] = acc[c];
  }
  __syncthreads();
  #pragma unroll
  for (int r = 0; r < 16; ++r) {
    int idx = r * 256 + tid;
    int n = idx >> 6, ch = idx & 63;
    bases[(size_t)(nb + n) * 64 + ch] = __fadd_rn(ob[n * 65 + ch], basesB[ch]);
  }
  #pragma unroll
  for (int r = 0; r < 8; ++r) {
    int idx = r * 256 + tid;
    int n = idx >> 5, ch = idx & 31;
    comb[(size_t)(nb + n) * 32 + ch] = __fadd_rn(oc[n * 33 + ch], combB[ch]);
  }
}

// fused: symnorm aggregation (edge-order scatter-add) -> einsum -> conv LIF -> c1 spike
__global__ __launch_bounds__(256) void k_aggconv(
    const float* __restrict__ bases, const float* __restrict__ comb,
    const float* __restrict__ dinv, const int* __restrict__ rowp,
    const int* __restrict__ col, const float* __restrict__ colw,
    const float* __restrict__ convB,
    float* __restrict__ c1_mem, float* __restrict__ c1_spk) {
  __shared__ float aggl[4][64];
  __shared__ float combl[4][32];
  int w = threadIdx.x >> 6;
  int m = threadIdx.x & 63;
  int d = blockIdx.x * 4 + w;
  float dd = dinv[d];
  int r0 = rowp[d], r1 = rowp[d + 1];
  float acc = 0.f;
  for (int r = r0; r < r1; ++r) {
    int s = col[r];
    float ew  = __fmul_rn(colw[r], dd);
    float upd = __fmul_rn(ew, bases[(size_t)s * 64 + m]);
    acc = __fadd_rn(acc, upd);
  }
  {
    float ew  = __fmul_rn(dd, dd);
    float upd = __fmul_rn(ew, bases[(size_t)d * 64 + m]);
    acc = __fadd_rn(acc, upd);
  }
  aggl[w][m] = acc;
  if (m < 32) combl[w][m] = comb[(size_t)d * 32 + m];
  __syncthreads();
  #pragma unroll
  for (int half = 0; half < 2; ++half) {
    int j = m + half * 64;
    int h = j >> 4, f = j & 15;
    float cv = 0.f;
    #pragma unroll
    for (int b = 0; b < 4; ++b)
      cv = __fadd_rn(cv, __fmul_rn(combl[w][h * 4 + b], aggl[w][b * 16 + f]));
    cv = __fadd_rn(cv, convB[j]);
    int idx = d * 128 + j;
    float cm = c1_mem[idx], cs = c1_spk[idx];
    float nm = __fadd_rn(__fmul_rn(__fmul_rn(cm, 0.2f), __fsub_rn(1.f, cs)), cv);
    c1_mem[idx] = nm;
    c1_spk[idx] = nm > 0.5f ? 1.f : 0.f;
  }
}

// one BLAS panel of the gates GEMM: part[z] = A[:, panel_z] @ B[panel_z, :]
// 128x128 tile, 8x8 frag (best FMA/LDS-byte ratio), DOUBLE-BUFFERED LDS:
// next tile's global loads issue before current tile's compute -> HBM latency
// hides under ~2048cy of FMA. Per-output chain: ascending k (bit-exact, unchanged).
__global__ __launch_bounds__(256, 4) void k_gpanel(
    const float* __restrict__ xl, const float* __restrict__ lh,
    const float* __restrict__ Wih, const float* __restrict__ Whh,
    float* __restrict__ part) {
  __shared__ __align__(16) float Ast[2][16][132];   // [buf][k][m] transposed
  __shared__ __align__(16) float Bs[2][16][132];    // [buf][k][n]
  const int tid = threadIdx.x;
  const int tx = tid & 15, ty = tid >> 4;
  const int n0 = blockIdx.x * 128;
  const int m0 = blockIdx.y * 128;
  const int z  = blockIdx.z;

  const float* Asrc; const float* Bsrc; int lda, k0, klen;
  if (z < 22) { Asrc = xl; Bsrc = Wih; lda = 8192; k0 = z * 384; klen = (z == 21) ? 128 : 384; }
  else        { Asrc = lh; Bsrc = Whh; lda = 512;  k0 = (z == 22) ? 0 : 384; klen = (z == 22) ? 384 : 128; }

  float acc[8][8];
  #pragma unroll
  for (int i = 0; i < 8; ++i)
    #pragma unroll
    for (int j = 0; j < 8; ++j) acc[i][j] = 0.f;

  const int arow = tid >> 1;            // 0..127
  const int acol = (tid & 1) * 8;       // 0 or 8
  const int brow = tid >> 5;            // 0..7 (and +8)
  const int bcol = (tid & 31) * 4;      // 0..124

  const int nkt = klen >> 4;

  // staging registers
  float4 av0, av1, bv0, bv1;

  // prologue: fetch tile 0 and stage to lds[0]
  {
    const float* srcA = Asrc + (size_t)(m0 + arow) * lda + k0 + acol;
    av0 = ((const float4*)srcA)[0];
    av1 = ((const float4*)srcA)[1];
    bv0 = *(const float4*)(Bsrc + (size_t)(k0 + brow) * 2048 + n0 + bcol);
    bv1 = *(const float4*)(Bsrc + (size_t)(k0 + brow + 8) * 2048 + n0 + bcol);
    Ast[0][acol + 0][arow] = av0.x; Ast[0][acol + 1][arow] = av0.y;
    Ast[0][acol + 2][arow] = av0.z; Ast[0][acol + 3][arow] = av0.w;
    Ast[0][acol + 4][arow] = av1.x; Ast[0][acol + 5][arow] = av1.y;
    Ast[0][acol + 6][arow] = av1.z; Ast[0][acol + 7][arow] = av1.w;
    *(float4*)&Bs[0][brow][bcol]     = bv0;
    *(float4*)&Bs[0][brow + 8][bcol] = bv1;
  }
  __syncthreads();

  int buf = 0;
  for (int kt = 0; kt < nkt; ++kt) {
    const bool more = (kt + 1 < nkt);
    if (more) {   // issue next-tile loads (latency hidden under compute below)
      const int kb = k0 + ((kt + 1) << 4);
      const float* srcA = Asrc + (size_t)(m0 + arow) * lda + kb + acol;
      av0 = ((const float4*)srcA)[0];
      av1 = ((const float4*)srcA)[1];
      bv0 = *(const float4*)(Bsrc + (size_t)(kb + brow) * 2048 + n0 + bcol);
      bv1 = *(const float4*)(Bsrc + (size_t)(kb + brow + 8) * 2048 + n0 + bcol);
    }
    // compute current tile
    #pragma unroll
    for (int kk = 0; kk < 16; ++kk) {
      const float4 a0 = *(const float4*)&Ast[buf][kk][ty * 4];
      const float4 a1 = *(const float4*)&Ast[buf][kk][64 + ty * 4];
      const float4 b0 = *(const float4*)&Bs[buf][kk][tx * 4];
      const float4 b1 = *(const float4*)&Bs[buf][kk][64 + tx * 4];
      const float av[8] = {a0.x, a0.y, a0.z, a0.w, a1.x, a1.y, a1.z, a1.w};
      const float bv[8] = {b0.x, b0.y, b0.z, b0.w, b1.x, b1.y, b1.z, b1.w};
      #pragma unroll
      for (int i = 0; i < 8; ++i)
        #pragma unroll
        for (int j = 0; j < 8; ++j)
          acc[i][j] = __fmaf_rn(av[i], bv[j], acc[i][j]);
    }
    if (more) {
      __syncthreads();                      // all waves done reading lds[buf]
      const int nb = buf ^ 1;
      Ast[nb][acol + 0][arow] = av0.x; Ast[nb][acol + 1][arow] = av0.y;
      Ast[nb][acol + 2][arow] = av0.z; Ast[nb][acol + 3][arow] = av0.w;
      Ast[nb][acol + 4][arow] = av1.x; Ast[nb][acol + 5][arow] = av1.y;
      Ast[nb][acol + 6][arow] = av1.z; Ast[nb][acol + 7][arow] = av1.w;
      *(float4*)&Bs[nb][brow][bcol]     = bv0;
      *(float4*)&Bs[nb][brow + 8][bcol] = bv1;
      __syncthreads();                      // next tile visible to all
      buf = nb;
    }
  }

  float* dstz = part + (size_t)z * GSTRIDE + (size_t)m0 * 2048 + n0;
  #pragma unroll
  for (int i = 0; i < 8; ++i) {
    const int mr = ((i >> 2) << 6) + ty * 4 + (i & 3);
    float* row = dstz + (size_t)mr * 2048;
    *(float4*)(row + tx * 4)      = make_float4(acc[i][0], acc[i][1], acc[i][2], acc[i][3]);
    *(float4*)(row + 64 + tx * 4) = make_float4(acc[i][4], acc[i][5], acc[i][6], acc[i][7]);
  }
}

// combine panel partials strictly left-to-right (matches verified "tih += accP" chain)
__global__ __launch_bounds__(256) void k_combine(
    const float* __restrict__ part, const float* __restrict__ bih,
    const float* __restrict__ bhh, float* __restrict__ gates) {
  const int idx = blockIdx.x * 256 + threadIdx.x;    // m*2048 + u
  const float* p = part + idx;
  float tih = p[0];
  #pragma unroll
  for (int zz = 1; zz < 22; ++zz) tih = __fadd_rn(tih, p[(size_t)zz * GSTRIDE]);
  const float thh = __fadd_rn(p[22u * GSTRIDE], p[23u * GSTRIDE]);
  const int u = idx & 2047;
  gates[idx] = __fadd_rn(__fadd_rn(__fadd_rn(tih, bih[u]), thh), bhh[u]);
}

// fused: gate spikes -> LSTM cell -> fc1 LIF -> fc2 LIF -> h2 accum
__global__ __launch_bounds__(256) void k_cell(
    const float* __restrict__ gates,
    float* __restrict__ lc, float* __restrict__ lh,
    const float* __restrict__ fc1W, const float* __restrict__ fc1b,
    const float* __restrict__ fc2W, const float* __restrict__ fc2b,
    float* __restrict__ h1_mem, float* __restrict__ h1_spk,
    float* __restrict__ h2_mem, float* __restrict__ h2_spk, float* __restrict__ h2_sum) {
  __shared__ float lhl[512];
  __shared__ float sp1l[256];
  const int s = blockIdx.x;
  const int p = threadIdx.x;
  #pragma unroll
  for (int half = 0; half < 2; ++half) {
    const int h = p + half * 256;
    const float giv = gates[(size_t)s * 2048 + h];
    const float gfv = gates[(size_t)s * 2048 + 512 + h];
    const float ggv = gates[(size_t)s * 2048 + 1024 + h];
    const float gov = gates[(size_t)s * 2048 + 1536 + h];
    const float iv = giv > 0.f ? 1.f : 0.f;
    const float fv = gfv > 0.f ? 1.f : 0.f;
    const float gv = ggv > 0.f ? 1.f : 0.f;
    const float ov = gov > 0.f ? 1.f : 0.f;
    const int li = s * 512 + h;
    const float lcv = __fadd_rn(__fmul_rn(fv, lc[li]), __fmul_rn(iv, gv));
    lc[li] = lcv;
    const float lhv = __fmul_rn(lcv, ov);
    lh[li] = lhv;
    lhl[h] = lhv;
  }
  __syncthreads();
  float a0 = 0.f, a1 = 0.f;
  #pragma unroll 8
  for (int q = 0; q < 384; ++q) a0 = __fmaf_rn(lhl[q], fc1W[q * 256 + p], a0);
  #pragma unroll 8
  for (int q = 384; q < 512; ++q) a1 = __fmaf_rn(lhl[q], fc1W[q * 256 + p], a1);
  const float dot1 = __fadd_rn(a0, a1);
  const int i1 = s * 256 + p;
  const float m1 = h1_mem[i1], s1o = h1_spk[i1];
  const float nm1 = __fadd_rn(__fadd_rn(__fmul_rn(__fmul_rn(m1, 0.2f), __fsub_rn(1.f, s1o)), dot1), fc1b[p]);
  h1_mem[i1] = nm1;
  const float sp1 = nm1 > 0.5f ? 1.f : 0.f;
  h1_spk[i1] = sp1;
  sp1l[p] = sp1;
  __syncthreads();
  if (p < 4) {
    float acc = 0.f;
    for (int q = 0; q < 256; ++q) acc = __fmaf_rn(sp1l[q], fc2W[q * 4 + p], acc);
    const int i2 = s * 4 + p;
    const float m2 = h2_mem[i2], s2o = h2_spk[i2];
    const float nm2 = __fadd_rn(__fadd_rn(__fmul_rn(__fmul_rn(m2, 0.2f), __fsub_rn(1.f, s2o)), acc), fc2b[p]);
    h2_mem[i2] = nm2;
    const float sp2 = nm2 > 0.5f ? 1.f : 0.f;
    h2_spk[i2] = sp2;
    h2_sum[i2] = __fadd_rn(h2_sum[i2], sp2);
  }
}

__global__ void k_out(const float* __restrict__ h2_sum, float* __restrict__ out) {
  int i = blockIdx.x * 256 + threadIdx.x;
  if (i < SG * 4) out[i] = __fmul_rn(h2_sum[i], 0.03125f);
}

// ---------------- launch ----------------
extern "C" void kernel_launch(void* const* d_in, const int* in_sizes, int n_in,
                              void* d_out, int out_size, void* d_ws, size_t ws_size,
                              hipStream_t stream) {
  const float* x      = (const float*)d_in[0];
  const int*   ei     = (const int*)  d_in[1];
  const float* encW   = (const float*)d_in[2];
  const float* encB   = (const float*)d_in[3];
  const float* basesW = (const float*)d_in[4];
  const float* basesB = (const float*)d_in[5];
  const float* combW  = (const float*)d_in[6];
  const float* combB  = (const float*)d_in[7];
  const float* convB  = (const float*)d_in[8];
  const float* Wih    = (const float*)d_in[9];
  const float* Whh    = (const float*)d_in[10];
  const float* bih    = (const float*)d_in[11];
  const float* bhh    = (const float*)d_in[12];
  const float* fc1W   = (const float*)d_in[13];
  const float* fc1b   = (const float*)d_in[14];
  const float* fc2W   = (const float*)d_in[15];
  const float* fc2b   = (const float*)d_in[16];

  float* ws = (float*)d_ws;
  float* enc_mem = ws + OFF_ENC_MEM;
  float* enc_spk = ws + OFF_ENC_SPK;
  float* c1_mem  = ws + OFF_C1_MEM;
  float* c1_spk  = ws + OFF_C1_SPK;   // xl
  float* lhp     = ws + OFF_LH;
  float* lcp     = ws + OFF_LC;
  float* h1_mem  = ws + OFF_H1_MEM;
  float* h1_spk  = ws + OFF_H1_SPK;
  float* h2_mem  = ws + OFF_H2_MEM;
  float* h2_spk  = ws + OFF_H2_SPK;
  float* h2_sum  = ws + OFF_H2_SUM;
  float* bases   = ws + OFF_BASES;
  float* comb    = ws + OFF_COMB;
  float* gates   = ws + OFF_GATES;
  float* partp   = ws + OFF_PART;
  float* dinv    = ws + OFF_DINV;
  float* colw    = ws + OFF_COLW;
  int* ibase = (int*)((char*)d_ws + (size_t)FLOAT_END * 4);
  int* deg  = ibase + IOFF_DEG;
  int* fill = ibase + IOFF_FILL;
  int* rowp = ibase + IOFF_ROWPTR;
  int* eid  = ibase + IOFF_EID;
  int* col  = ibase + IOFF_COL;

  hipMemsetAsync(ws, 0, (size_t)ZERO_FLOATS * 4, stream);
  hipMemsetAsync(ibase, 0, 32768 * 4, stream);

  k_deg    <<<NE / 256, 256, 0, stream>>>(ei, deg);
  k_dinv   <<<NN / 256, 256, 0, stream>>>(deg, dinv);
  k_scan   <<<1, 1024, 0, stream>>>(deg, rowp);
  k_scatter<<<NE / 256, 256, 0, stream>>>(ei, rowp, fill, eid);
  k_sortadj<<<NN / 256, 256, 0, stream>>>(rowp, eid, ei, dinv, col, colw);

  for (int t = 0; t < TSTEPS; ++t) {
    k_enc       <<<NN / 2, 256, 0, stream>>>(x, encW, encB, enc_mem, enc_spk, t);
    k_bases_comb<<<NN / 64, 256, 0, stream>>>(enc_spk, basesW, basesB, combW, combB, bases, comb);
    k_aggconv   <<<NN / 4, 256, 0, stream>>>(bases, comb, dinv, rowp, col, colw, convB, c1_mem, c1_spk);
    k_gpanel    <<<dim3(16, 2, NPANEL), 256, 0, stream>>>(c1_spk, lhp, Wih, Whh, partp);
    k_combine   <<<2048, 256, 0, stream>>>(partp, bih, bhh, gates);
    k_cell      <<<SG, 256, 0, stream>>>(gates, lcp, lhp, fc1W, fc1b, fc2W, fc2b,
                                         h1_mem, h1_spk, h2_mem, h2_spk, h2_sum);
  }
  k_out<<<4, 256, 0, stream>>>(h2_sum, (float*)d_out);
}

// Round 4
// 8409.078 us; speedup vs baseline: 7.0669x; 7.0669x over previous
//
#include <hip/hip_runtime.h>

// ---------------- problem constants ----------------
#define NN      16384      // total nodes
#define TSTEPS  32
#define SG      256        // graphs
#define NE      262144
#define NPANEL  24         // 22 panels for xl@Wih (21x384 + 128) + 2 for lh@Whh (384+128)
#define GSTRIDE 524288u    // 256*2048 floats per panel partial

// ---------------- workspace layout (float offsets) ----------------
#define OFF_ENC_MEM   0u
#define OFF_ENC_SPK   2097152u
#define OFF_C1_MEM    4194304u
#define OFF_C1_SPK    6291456u     // == xl [256][8192]
#define OFF_LH        8388608u
#define OFF_LC        8519680u
#define OFF_H1_MEM    8650752u
#define OFF_H1_SPK    8716288u
#define OFF_H2_MEM    8781824u
#define OFF_H2_SPK    8782848u
#define OFF_H2_SUM    8783872u
#define ZERO_FLOATS   8784896u     // everything below here zeroed each launch
#define OFF_BASES     8784896u
#define OFF_COMB      9833472u
#define OFF_GATES     10357760u    // 256 x 2048
#define OFF_PART      10882048u    // 24 x 256 x 2048 panel partials
#define OFF_DINV      23464960u
#define OFF_COLW      23481344u
#define FLOAT_END     23743488u
// int region (offsets from ibase)
#define IOFF_DEG      0
#define IOFF_FILL     16384
#define IOFF_ROWPTR   32768
#define IOFF_EID      49153
#define IOFF_COL      311297
#define INT_COUNT     573441

// ---------------- graph preprocessing ----------------
__global__ void k_deg(const int* __restrict__ ei, int* __restrict__ deg) {
  int e = blockIdx.x * 256 + threadIdx.x;
  if (e < NE) atomicAdd(&deg[ei[NE + e]], 1);
}

__global__ void k_dinv(const int* __restrict__ deg, float* __restrict__ dinv) {
  int n = blockIdx.x * 256 + threadIdx.x;
  if (n < NN) dinv[n] = __fdiv_rn(1.0f, __fsqrt_rn((float)(deg[n] + 1)));  // +1 self-loop
}

__global__ void k_scan(const int* __restrict__ deg, int* __restrict__ rowp) {
  __shared__ int sdata[1024];
  int tid = threadIdx.x;
  int base = tid * 16;
  int loc[16];
  int sum = 0;
  #pragma unroll
  for (int i = 0; i < 16; ++i) { loc[i] = sum; sum += deg[base + i]; }
  sdata[tid] = sum;
  __syncthreads();
  for (int off = 1; off < 1024; off <<= 1) {
    int v = 0;
    if (tid >= off) v = sdata[tid - off];
    __syncthreads();
    sdata[tid] += v;
    __syncthreads();
  }
  int excl = (tid == 0) ? 0 : sdata[tid - 1];
  #pragma unroll
  for (int i = 0; i < 16; ++i) rowp[base + i] = excl + loc[i];
  if (tid == 1023) rowp[NN] = sdata[1023];
}

__global__ void k_scatter(const int* __restrict__ ei, const int* __restrict__ rowp,
                          int* __restrict__ fill, int* __restrict__ eid) {
  int e = blockIdx.x * 256 + threadIdx.x;
  if (e >= NE) return;
  int d = ei[NE + e];
  int pos = rowp[d] + atomicAdd(&fill[d], 1);
  eid[pos] = e;
}

// sort each adjacency list by EDGE ID (unique keys) -> summation order == scatter-add order
__global__ void k_sortadj(const int* __restrict__ rowp, int* __restrict__ eid,
                          const int* __restrict__ ei, const float* __restrict__ dinv,
                          int* __restrict__ col, float* __restrict__ colw) {
  int d = blockIdx.x * 256 + threadIdx.x;
  if (d >= NN) return;
  int r0 = rowp[d], r1 = rowp[d + 1];
  for (int i = r0 + 1; i < r1; ++i) {
    int key = eid[i];
    int j = i - 1;
    while (j >= r0 && eid[j] > key) { eid[j + 1] = eid[j]; --j; }
    eid[j + 1] = key;
  }
  for (int i = r0; i < r1; ++i) {
    int s = ei[eid[i]];
    col[i] = s;
    colw[i] = dinv[s];
  }
}

// ---------------- per-timestep kernels ----------------
// enc LIF (2 nodes/block; x staged through LDS to kill strided scalar loads)
__global__ __launch_bounds__(256) void k_enc(
    const float* __restrict__ x, const float* __restrict__ encW, const float* __restrict__ encB,
    float* __restrict__ enc_mem, float* __restrict__ enc_spk, int t) {
  __shared__ float xs[2][8];
  int tid = threadIdx.x;
  int nb = blockIdx.x * 2;
  if (tid < 16)
    xs[tid >> 3][tid & 7] = x[(size_t)(nb + (tid >> 3)) * 256 + (size_t)(tid & 7) * 32 + t];
  __syncthreads();
  int nl = tid >> 7, j = tid & 127;
  int idx = (nb + nl) * 128 + j;
  float dot = 0.f;
  #pragma unroll
  for (int c = 0; c < 8; ++c) dot = __fmaf_rn(xs[nl][c], encW[c * 128 + j], dot);
  float m = enc_mem[idx], s = enc_spk[idx];
  float nm = __fadd_rn(__fadd_rn(__fmul_rn(__fmul_rn(m, 0.2f), __fsub_rn(1.f, s)), dot), encB[j]);
  enc_mem[idx] = nm;
  enc_spk[idx] = nm > 0.5f ? 1.f : 0.f;
}

// bases = spk @ bases_W + b ; comb = spk @ comb_W + b
__global__ __launch_bounds__(256) void k_bases_comb(
    const float* __restrict__ enc_spk,
    const float* __restrict__ basesW, const float* __restrict__ basesB,
    const float* __restrict__ combW, const float* __restrict__ combB,
    float* __restrict__ bases, float* __restrict__ comb) {
  __shared__ float sp[64 * 129];   // [node][j], pad 129 -> (n+j)%32 banks
  __shared__ float ob[64 * 65];    // bases out [node][ch], pad 65
  __shared__ float oc[64 * 33];    // comb out [node][ch], pad 33
  const int tid = threadIdx.x;
  const int nb = blockIdx.x * 64;
  #pragma unroll 4
  for (int k = 0; k < 32; ++k) {
    int idx = k * 256 + tid;
    int n = idx >> 7, j = idx & 127;
    sp[n * 129 + j] = enc_spk[(size_t)nb * 128 + idx];
  }
  __syncthreads();
  const int lane = tid & 63;
  const int w = tid >> 6;
  const float* spn = sp + lane * 129;
  if (w < 2) {
    const int ch0 = w * 32;
    const float* Wp = basesW + ch0;
    float acc[32];
    #pragma unroll
    for (int c = 0; c < 32; ++c) acc[c] = 0.f;
    for (int j = 0; j < 128; ++j) {
      const float s = spn[j];
      const float* wr = Wp + j * 64;     // lane-invariant -> scalar loads
      #pragma unroll
      for (int c = 0; c < 32; ++c) acc[c] = __fmaf_rn(s, wr[c], acc[c]);
    }
    #pragma unroll
    for (int c = 0; c < 32; ++c) ob[lane * 65 + ch0 + c] = acc[c];
  } else {
    const int ch0 = (w - 2) * 16;
    const float* Wp = combW + ch0;
    float acc[16];
    #pragma unroll
    for (int c = 0; c < 16; ++c) acc[c] = 0.f;
    for (int j = 0; j < 128; ++j) {
      const float s = spn[j];
      const float* wr = Wp + j * 32;
      #pragma unroll
      for (int c = 0; c < 16; ++c) acc[c] = __fmaf_rn(s, wr[c], acc[c]);
    }
    #pragma unroll
    for (int c = 0; c < 16; ++c) oc[lane * 33 + ch0 + c] = acc[c];
  }
  __syncthreads();
  #pragma unroll
  for (int r = 0; r < 16; ++r) {
    int idx = r * 256 + tid;
    int n = idx >> 6, ch = idx & 63;
    bases[(size_t)(nb + n) * 64 + ch] = __fadd_rn(ob[n * 65 + ch], basesB[ch]);
  }
  #pragma unroll
  for (int r = 0; r < 8; ++r) {
    int idx = r * 256 + tid;
    int n = idx >> 5, ch = idx & 31;
    comb[(size_t)(nb + n) * 32 + ch] = __fadd_rn(oc[n * 33 + ch], combB[ch]);
  }
}

// fused: symnorm aggregation (edge-order scatter-add) -> einsum -> conv LIF -> c1 spike
__global__ __launch_bounds__(256) void k_aggconv(
    const float* __restrict__ bases, const float* __restrict__ comb,
    const float* __restrict__ dinv, const int* __restrict__ rowp,
    const int* __restrict__ col, const float* __restrict__ colw,
    const float* __restrict__ convB,
    float* __restrict__ c1_mem, float* __restrict__ c1_spk) {
  __shared__ float aggl[4][64];
  __shared__ float combl[4][32];
  int w = threadIdx.x >> 6;
  int m = threadIdx.x & 63;
  int d = blockIdx.x * 4 + w;
  float dd = dinv[d];
  int r0 = rowp[d], r1 = rowp[d + 1];
  float acc = 0.f;
  for (int r = r0; r < r1; ++r) {
    int s = col[r];
    float ew  = __fmul_rn(colw[r], dd);
    float upd = __fmul_rn(ew, bases[(size_t)s * 64 + m]);
    acc = __fadd_rn(acc, upd);
  }
  {
    float ew  = __fmul_rn(dd, dd);
    float upd = __fmul_rn(ew, bases[(size_t)d * 64 + m]);
    acc = __fadd_rn(acc, upd);
  }
  aggl[w][m] = acc;
  if (m < 32) combl[w][m] = comb[(size_t)d * 32 + m];
  __syncthreads();
  #pragma unroll
  for (int half = 0; half < 2; ++half) {
    int j = m + half * 64;
    int h = j >> 4, f = j & 15;
    float cv = 0.f;
    #pragma unroll
    for (int b = 0; b < 4; ++b)
      cv = __fadd_rn(cv, __fmul_rn(combl[w][h * 4 + b], aggl[w][b * 16 + f]));
    cv = __fadd_rn(cv, convB[j]);
    int idx = d * 128 + j;
    float cm = c1_mem[idx], cs = c1_spk[idx];
    float nm = __fadd_rn(__fmul_rn(__fmul_rn(cm, 0.2f), __fsub_rn(1.f, cs)), cv);
    c1_mem[idx] = nm;
    c1_spk[idx] = nm > 0.5f ? 1.f : 0.f;
  }
}

// one BLAS panel of the gates GEMM: part[z] = A[:, panel_z] @ B[panel_z, :]
// 128x128 tile, 8x8 frag, double-buffered LDS with ONE barrier per K-tile:
// next tile's global loads issue before compute (latency hides under ~2048cy FMA),
// staged regs written to the alternate LDS buffer after compute.
// NO min-waves launch bound: unified VGPR+AGPR budget must fit acc(64)+staging(16)
// without spilling (R3 post-mortem: (256,4) forced 128-reg budget -> scratch spill).
// Per-output chain: single FMA chain ascending k within the panel (bit-exact).
__global__ __launch_bounds__(256) void k_gpanel(
    const float* __restrict__ xl, const float* __restrict__ lh,
    const float* __restrict__ Wih, const float* __restrict__ Whh,
    float* __restrict__ part) {
  __shared__ __align__(16) float Ast[2][16][132];   // [buf][k][m] transposed
  __shared__ __align__(16) float Bs[2][16][132];    // [buf][k][n]
  const int tid = threadIdx.x;
  const int tx = tid & 15, ty = tid >> 4;
  const int n0 = blockIdx.x * 128;
  const int m0 = blockIdx.y * 128;
  const int z  = blockIdx.z;

  const float* Asrc; const float* Bsrc; int lda, k0, klen;
  if (z < 22) { Asrc = xl; Bsrc = Wih; lda = 8192; k0 = z * 384; klen = (z == 21) ? 128 : 384; }
  else        { Asrc = lh; Bsrc = Whh; lda = 512;  k0 = (z == 22) ? 0 : 384; klen = (z == 22) ? 384 : 128; }

  float acc[8][8];
  #pragma unroll
  for (int i = 0; i < 8; ++i)
    #pragma unroll
    for (int j = 0; j < 8; ++j) acc[i][j] = 0.f;

  const int arow = tid >> 1;            // 0..127
  const int acol = (tid & 1) * 8;       // 0 or 8
  const int brow = tid >> 5;            // 0..7 (and +8)
  const int bcol = (tid & 31) * 4;      // 0..124

  const int nkt = klen >> 4;

  float4 av0, av1, bv0, bv1;            // staging (16 VGPRs, live across compute)

  // prologue: fetch tile 0 and stage to lds[0]
  {
    const float* srcA = Asrc + (size_t)(m0 + arow) * lda + k0 + acol;
    av0 = ((const float4*)srcA)[0];
    av1 = ((const float4*)srcA)[1];
    bv0 = *(const float4*)(Bsrc + (size_t)(k0 + brow) * 2048 + n0 + bcol);
    bv1 = *(const float4*)(Bsrc + (size_t)(k0 + brow + 8) * 2048 + n0 + bcol);
    Ast[0][acol + 0][arow] = av0.x; Ast[0][acol + 1][arow] = av0.y;
    Ast[0][acol + 2][arow] = av0.z; Ast[0][acol + 3][arow] = av0.w;
    Ast[0][acol + 4][arow] = av1.x; Ast[0][acol + 5][arow] = av1.y;
    Ast[0][acol + 6][arow] = av1.z; Ast[0][acol + 7][arow] = av1.w;
    *(float4*)&Bs[0][brow][bcol]     = bv0;
    *(float4*)&Bs[0][brow + 8][bcol] = bv1;
  }
  __syncthreads();

  int buf = 0;
  for (int kt = 0; kt < nkt; ++kt) {
    const bool more = (kt + 1 < nkt);
    if (more) {   // issue next-tile loads; latency hidden under compute below
      const int kb = k0 + ((kt + 1) << 4);
      const float* srcA = Asrc + (size_t)(m0 + arow) * lda + kb + acol;
      av0 = ((const float4*)srcA)[0];
      av1 = ((const float4*)srcA)[1];
      bv0 = *(const float4*)(Bsrc + (size_t)(kb + brow) * 2048 + n0 + bcol);
      bv1 = *(const float4*)(Bsrc + (size_t)(kb + brow + 8) * 2048 + n0 + bcol);
    }
    // compute current tile
    #pragma unroll
    for (int kk = 0; kk < 16; ++kk) {
      const float4 a0 = *(const float4*)&Ast[buf][kk][ty * 4];
      const float4 a1 = *(const float4*)&Ast[buf][kk][64 + ty * 4];
      const float4 b0 = *(const float4*)&Bs[buf][kk][tx * 4];
      const float4 b1 = *(const float4*)&Bs[buf][kk][64 + tx * 4];
      const float av[8] = {a0.x, a0.y, a0.z, a0.w, a1.x, a1.y, a1.z, a1.w};
      const float bv[8] = {b0.x, b0.y, b0.z, b0.w, b1.x, b1.y, b1.z, b1.w};
      #pragma unroll
      for (int i = 0; i < 8; ++i)
        #pragma unroll
        for (int j = 0; j < 8; ++j)
          acc[i][j] = __fmaf_rn(av[i], bv[j], acc[i][j]);
    }
    if (more) {
      // write staged tile into the other buffer. Safe without a pre-barrier:
      // all waves finished READING buf^1 before the barrier that ended iter kt-1.
      const int nb = buf ^ 1;
      Ast[nb][acol + 0][arow] = av0.x; Ast[nb][acol + 1][arow] = av0.y;
      Ast[nb][acol + 2][arow] = av0.z; Ast[nb][acol + 3][arow] = av0.w;
      Ast[nb][acol + 4][arow] = av1.x; Ast[nb][acol + 5][arow] = av1.y;
      Ast[nb][acol + 6][arow] = av1.z; Ast[nb][acol + 7][arow] = av1.w;
      *(float4*)&Bs[nb][brow][bcol]     = bv0;
      *(float4*)&Bs[nb][brow + 8][bcol] = bv1;
      __syncthreads();                  // writes visible; everyone done with buf
      buf = nb;
    }
  }

  float* dstz = part + (size_t)z * GSTRIDE + (size_t)m0 * 2048 + n0;
  #pragma unroll
  for (int i = 0; i < 8; ++i) {
    const int mr = ((i >> 2) << 6) + ty * 4 + (i & 3);
    float* row = dstz + (size_t)mr * 2048;
    *(float4*)(row + tx * 4)      = make_float4(acc[i][0], acc[i][1], acc[i][2], acc[i][3]);
    *(float4*)(row + 64 + tx * 4) = make_float4(acc[i][4], acc[i][5], acc[i][6], acc[i][7]);
  }
}

// combine panel partials strictly left-to-right (matches verified "tih += accP" chain)
__global__ __launch_bounds__(256) void k_combine(
    const float* __restrict__ part, const float* __restrict__ bih,
    const float* __restrict__ bhh, float* __restrict__ gates) {
  const int idx = blockIdx.x * 256 + threadIdx.x;    // m*2048 + u
  const float* p = part + idx;
  float tih = p[0];
  #pragma unroll
  for (int zz = 1; zz < 22; ++zz) tih = __fadd_rn(tih, p[(size_t)zz * GSTRIDE]);
  const float thh = __fadd_rn(p[22u * GSTRIDE], p[23u * GSTRIDE]);
  const int u = idx & 2047;
  gates[idx] = __fadd_rn(__fadd_rn(__fadd_rn(tih, bih[u]), thh), bhh[u]);
}

// fused: gate spikes -> LSTM cell -> fc1 LIF -> fc2 LIF -> h2 accum
__global__ __launch_bounds__(256) void k_cell(
    const float* __restrict__ gates,
    float* __restrict__ lc, float* __restrict__ lh,
    const float* __restrict__ fc1W, const float* __restrict__ fc1b,
    const float* __restrict__ fc2W, const float* __restrict__ fc2b,
    float* __restrict__ h1_mem, float* __restrict__ h1_spk,
    float* __restrict__ h2_mem, float* __restrict__ h2_spk, float* __restrict__ h2_sum) {
  __shared__ float lhl[512];
  __shared__ float sp1l[256];
  const int s = blockIdx.x;
  const int p = threadIdx.x;
  #pragma unroll
  for (int half = 0; half < 2; ++half) {
    const int h = p + half * 256;
    const float giv = gates[(size_t)s * 2048 + h];
    const float gfv = gates[(size_t)s * 2048 + 512 + h];
    const float ggv = gates[(size_t)s * 2048 + 1024 + h];
    const float gov = gates[(size_t)s * 2048 + 1536 + h];
    const float iv = giv > 0.f ? 1.f : 0.f;
    const float fv = gfv > 0.f ? 1.f : 0.f;
    const float gv = ggv > 0.f ? 1.f : 0.f;
    const float ov = gov > 0.f ? 1.f : 0.f;
    const int li = s * 512 + h;
    const float lcv = __fadd_rn(__fmul_rn(fv, lc[li]), __fmul_rn(iv, gv));
    lc[li] = lcv;
    const float lhv = __fmul_rn(lcv, ov);
    lh[li] = lhv;
    lhl[h] = lhv;
  }
  __syncthreads();
  float a0 = 0.f, a1 = 0.f;
  #pragma unroll 8
  for (int q = 0; q < 384; ++q) a0 = __fmaf_rn(lhl[q], fc1W[q * 256 + p], a0);
  #pragma unroll 8
  for (int q = 384; q < 512; ++q) a1 = __fmaf_rn(lhl[q], fc1W[q * 256 + p], a1);
  const float dot1 = __fadd_rn(a0, a1);
  const int i1 = s * 256 + p;
  const float m1 = h1_mem[i1], s1o = h1_spk[i1];
  const float nm1 = __fadd_rn(__fadd_rn(__fmul_rn(__fmul_rn(m1, 0.2f), __fsub_rn(1.f, s1o)), dot1), fc1b[p]);
  h1_mem[i1] = nm1;
  const float sp1 = nm1 > 0.5f ? 1.f : 0.f;
  h1_spk[i1] = sp1;
  sp1l[p] = sp1;
  __syncthreads();
  if (p < 4) {
    float acc = 0.f;
    for (int q = 0; q < 256; ++q) acc = __fmaf_rn(sp1l[q], fc2W[q * 4 + p], acc);
    const int i2 = s * 4 + p;
    const float m2 = h2_mem[i2], s2o = h2_spk[i2];
    const float nm2 = __fadd_rn(__fadd_rn(__fmul_rn(__fmul_rn(m2, 0.2f), __fsub_rn(1.f, s2o)), acc), fc2b[p]);
    h2_mem[i2] = nm2;
    const float sp2 = nm2 > 0.5f ? 1.f : 0.f;
    h2_spk[i2] = sp2;
    h2_sum[i2] = __fadd_rn(h2_sum[i2], sp2);
  }
}

__global__ void k_out(const float* __restrict__ h2_sum, float* __restrict__ out) {
  int i = blockIdx.x * 256 + threadIdx.x;
  if (i < SG * 4) out[i] = __fmul_rn(h2_sum[i], 0.03125f);
}

// ---------------- launch ----------------
extern "C" void kernel_launch(void* const* d_in, const int* in_sizes, int n_in,
                              void* d_out, int out_size, void* d_ws, size_t ws_size,
                              hipStream_t stream) {
  const float* x      = (const float*)d_in[0];
  const int*   ei     = (const int*)  d_in[1];
  const float* encW   = (const float*)d_in[2];
  const float* encB   = (const float*)d_in[3];
  const float* basesW = (const float*)d_in[4];
  const float* basesB = (const float*)d_in[5];
  const float* combW  = (const float*)d_in[6];
  const float* combB  = (const float*)d_in[7];
  const float* convB  = (const float*)d_in[8];
  const float* Wih    = (const float*)d_in[9];
  const float* Whh    = (const float*)d_in[10];
  const float* bih    = (const float*)d_in[11];
  const float* bhh    = (const float*)d_in[12];
  const float* fc1W   = (const float*)d_in[13];
  const float* fc1b   = (const float*)d_in[14];
  const float* fc2W   = (const float*)d_in[15];
  const float* fc2b   = (const float*)d_in[16];

  float* ws = (float*)d_ws;
  float* enc_mem = ws + OFF_ENC_MEM;
  float* enc_spk = ws + OFF_ENC_SPK;
  float* c1_mem  = ws + OFF_C1_MEM;
  float* c1_spk  = ws + OFF_C1_SPK;   // xl
  float* lhp     = ws + OFF_LH;
  float* lcp     = ws + OFF_LC;
  float* h1_mem  = ws + OFF_H1_MEM;
  float* h1_spk  = ws + OFF_H1_SPK;
  float* h2_mem  = ws + OFF_H2_MEM;
  float* h2_spk  = ws + OFF_H2_SPK;
  float* h2_sum  = ws + OFF_H2_SUM;
  float* bases   = ws + OFF_BASES;
  float* comb    = ws + OFF_COMB;
  float* gates   = ws + OFF_GATES;
  float* partp   = ws + OFF_PART;
  float* dinv    = ws + OFF_DINV;
  float* colw    = ws + OFF_COLW;
  int* ibase = (int*)((char*)d_ws + (size_t)FLOAT_END * 4);
  int* deg  = ibase + IOFF_DEG;
  int* fill = ibase + IOFF_FILL;
  int* rowp = ibase + IOFF_ROWPTR;
  int* eid  = ibase + IOFF_EID;
  int* col  = ibase + IOFF_COL;

  hipMemsetAsync(ws, 0, (size_t)ZERO_FLOATS * 4, stream);
  hipMemsetAsync(ibase, 0, 32768 * 4, stream);

  k_deg    <<<NE / 256, 256, 0, stream>>>(ei, deg);
  k_dinv   <<<NN / 256, 256, 0, stream>>>(deg, dinv);
  k_scan   <<<1, 1024, 0, stream>>>(deg, rowp);
  k_scatter<<<NE / 256, 256, 0, stream>>>(ei, rowp, fill, eid);
  k_sortadj<<<NN / 256, 256, 0, stream>>>(rowp, eid, ei, dinv, col, colw);

  for (int t = 0; t < TSTEPS; ++t) {
    k_enc       <<<NN / 2, 256, 0, stream>>>(x, encW, encB, enc_mem, enc_spk, t);
    k_bases_comb<<<NN / 64, 256, 0, stream>>>(enc_spk, basesW, basesB, combW, combB, bases, comb);
    k_aggconv   <<<NN / 4, 256, 0, stream>>>(bases, comb, dinv, rowp, col, colw, convB, c1_mem, c1_spk);
    k_gpanel    <<<dim3(16, 2, NPANEL), 256, 0, stream>>>(c1_spk, lhp, Wih, Whh, partp);
    k_combine   <<<2048, 256, 0, stream>>>(partp, bih, bhh, gates);
    k_cell      <<<SG, 256, 0, stream>>>(gates, lcp, lhp, fc1W, fc1b, fc2W, fc2b,
                                         h1_mem, h1_spk, h2_mem, h2_spk, h2_sum);
  }
  k_out<<<4, 256, 0, stream>>>(h2_sum, (float*)d_out);
}

// Round 5
// 6935.632 us; speedup vs baseline: 8.5683x; 1.2124x over previous
//
#include <hip/hip_runtime.h>

// ---------------- problem constants ----------------
#define NN      16384      // total nodes
#define TSTEPS  32
#define SG      256        // graphs
#define NE      262144
#define NPANEL  24         // 22 panels for xl@Wih (21x384 + 128) + 2 for lh@Whh (384+128)
#define GSTRIDE 524288u    // 256*2048 floats per panel partial

// ---------------- workspace layout (float offsets) ----------------
#define OFF_ENC_MEM   0u
#define OFF_ENC_SPK   2097152u
#define OFF_C1_MEM    4194304u
#define OFF_C1_SPK    6291456u     // == xl [256][8192]
#define OFF_LH        8388608u
#define OFF_LC        8519680u
#define OFF_H1_MEM    8650752u
#define OFF_H1_SPK    8716288u
#define OFF_H2_MEM    8781824u
#define OFF_H2_SPK    8782848u
#define OFF_H2_SUM    8783872u
#define ZERO_FLOATS   8784896u     // everything below here zeroed each launch
#define OFF_BASES     8784896u
#define OFF_COMB      9833472u
#define OFF_GATES     10357760u    // 256 x 2048
#define OFF_PART      10882048u    // 24 x 256 x 2048 panel partials
#define OFF_DINV      23464960u
#define OFF_COLW      23481344u
#define FLOAT_END     23743488u
// int region (offsets from ibase)
#define IOFF_DEG      0
#define IOFF_FILL     16384
#define IOFF_ROWPTR   32768
#define IOFF_EID      49153
#define IOFF_COL      311297
#define INT_COUNT     573441

// ---------------- graph preprocessing ----------------
__global__ void k_deg(const int* __restrict__ ei, int* __restrict__ deg) {
  int e = blockIdx.x * 256 + threadIdx.x;
  if (e < NE) atomicAdd(&deg[ei[NE + e]], 1);
}

__global__ void k_dinv(const int* __restrict__ deg, float* __restrict__ dinv) {
  int n = blockIdx.x * 256 + threadIdx.x;
  if (n < NN) dinv[n] = __fdiv_rn(1.0f, __fsqrt_rn((float)(deg[n] + 1)));  // +1 self-loop
}

__global__ void k_scan(const int* __restrict__ deg, int* __restrict__ rowp) {
  __shared__ int sdata[1024];
  int tid = threadIdx.x;
  int base = tid * 16;
  int loc[16];
  int sum = 0;
  #pragma unroll
  for (int i = 0; i < 16; ++i) { loc[i] = sum; sum += deg[base + i]; }
  sdata[tid] = sum;
  __syncthreads();
  for (int off = 1; off < 1024; off <<= 1) {
    int v = 0;
    if (tid >= off) v = sdata[tid - off];
    __syncthreads();
    sdata[tid] += v;
    __syncthreads();
  }
  int excl = (tid == 0) ? 0 : sdata[tid - 1];
  #pragma unroll
  for (int i = 0; i < 16; ++i) rowp[base + i] = excl + loc[i];
  if (tid == 1023) rowp[NN] = sdata[1023];
}

__global__ void k_scatter(const int* __restrict__ ei, const int* __restrict__ rowp,
                          int* __restrict__ fill, int* __restrict__ eid) {
  int e = blockIdx.x * 256 + threadIdx.x;
  if (e >= NE) return;
  int d = ei[NE + e];
  int pos = rowp[d] + atomicAdd(&fill[d], 1);
  eid[pos] = e;
}

// sort each adjacency list by EDGE ID (unique keys) -> summation order == scatter-add order
__global__ void k_sortadj(const int* __restrict__ rowp, int* __restrict__ eid,
                          const int* __restrict__ ei, const float* __restrict__ dinv,
                          int* __restrict__ col, float* __restrict__ colw) {
  int d = blockIdx.x * 256 + threadIdx.x;
  if (d >= NN) return;
  int r0 = rowp[d], r1 = rowp[d + 1];
  for (int i = r0 + 1; i < r1; ++i) {
    int key = eid[i];
    int j = i - 1;
    while (j >= r0 && eid[j] > key) { eid[j + 1] = eid[j]; --j; }
    eid[j + 1] = key;
  }
  for (int i = r0; i < r1; ++i) {
    int s = ei[eid[i]];
    col[i] = s;
    colw[i] = dinv[s];
  }
}

// ---------------- per-timestep kernels ----------------
// FUSED: enc LIF (in-block, 64 nodes) -> bases/comb GEMMs.
// enc chain identical to old k_enc: dot ascending c, then LIF update, spike.
// Saves one dispatch + the 8.4MB/step enc_spk global re-read.
__global__ __launch_bounds__(256) void k_bases_comb(
    const float* __restrict__ x, const float* __restrict__ encW, const float* __restrict__ encB,
    float* __restrict__ enc_mem, float* __restrict__ enc_spk,
    const float* __restrict__ basesW, const float* __restrict__ basesB,
    const float* __restrict__ combW, const float* __restrict__ combB,
    float* __restrict__ bases, float* __restrict__ comb, int t) {
  __shared__ float xs[64][8];      // staged inputs for this block's 64 nodes
  __shared__ float sp[64 * 129];   // [node][j], pad 129 -> (n+j)%32 banks
  __shared__ float ob[64 * 65];    // bases out [node][ch], pad 65
  __shared__ float oc[64 * 33];    // comb out [node][ch], pad 33
  const int tid = threadIdx.x;
  const int nb = blockIdx.x * 64;
  // stage x: 64 nodes x 8 channels
  #pragma unroll
  for (int k = 0; k < 2; ++k) {
    int idx = k * 256 + tid;
    int n = idx >> 3, c = idx & 7;
    xs[n][c] = x[(size_t)(nb + n) * 256 + (size_t)c * 32 + t];
  }
  __syncthreads();
  // enc LIF for this block's 64 nodes (identical op chain to old k_enc)
  #pragma unroll 4
  for (int k = 0; k < 32; ++k) {
    int idx = k * 256 + tid;
    int n = idx >> 7, j = idx & 127;   // n uniform per wave -> xs broadcast reads
    int gidx = nb * 128 + idx;
    float dot = 0.f;
    #pragma unroll
    for (int c = 0; c < 8; ++c) dot = __fmaf_rn(xs[n][c], encW[c * 128 + j], dot);
    float m = enc_mem[gidx], s = enc_spk[gidx];
    float nm = __fadd_rn(__fadd_rn(__fmul_rn(__fmul_rn(m, 0.2f), __fsub_rn(1.f, s)), dot), encB[j]);
    enc_mem[gidx] = nm;
    float spk = nm > 0.5f ? 1.f : 0.f;
    enc_spk[gidx] = spk;
    sp[n * 129 + j] = spk;
  }
  __syncthreads();
  const int lane = tid & 63;
  const int w = tid >> 6;
  const float* spn = sp + lane * 129;
  if (w < 2) {
    const int ch0 = w * 32;
    const float* Wp = basesW + ch0;
    float acc[32];
    #pragma unroll
    for (int c = 0; c < 32; ++c) acc[c] = 0.f;
    for (int j = 0; j < 128; ++j) {
      const float s = spn[j];
      const float* wr = Wp + j * 64;     // lane-invariant -> scalar loads
      #pragma unroll
      for (int c = 0; c < 32; ++c) acc[c] = __fmaf_rn(s, wr[c], acc[c]);
    }
    #pragma unroll
    for (int c = 0; c < 32; ++c) ob[lane * 65 + ch0 + c] = acc[c];
  } else {
    const int ch0 = (w - 2) * 16;
    const float* Wp = combW + ch0;
    float acc[16];
    #pragma unroll
    for (int c = 0; c < 16; ++c) acc[c] = 0.f;
    for (int j = 0; j < 128; ++j) {
      const float s = spn[j];
      const float* wr = Wp + j * 32;
      #pragma unroll
      for (int c = 0; c < 16; ++c) acc[c] = __fmaf_rn(s, wr[c], acc[c]);
    }
    #pragma unroll
    for (int c = 0; c < 16; ++c) oc[lane * 33 + ch0 + c] = acc[c];
  }
  __syncthreads();
  // coalesced stores with bias
  #pragma unroll
  for (int r = 0; r < 16; ++r) {
    int idx = r * 256 + tid;
    int n = idx >> 6, ch = idx & 63;
    bases[(size_t)(nb + n) * 64 + ch] = __fadd_rn(ob[n * 65 + ch], basesB[ch]);
  }
  #pragma unroll
  for (int r = 0; r < 8; ++r) {
    int idx = r * 256 + tid;
    int n = idx >> 5, ch = idx & 31;
    comb[(size_t)(nb + n) * 32 + ch] = __fadd_rn(oc[n * 33 + ch], combB[ch]);
  }
}

// fused: symnorm aggregation (edge-order scatter-add) -> einsum -> conv LIF -> c1 spike
__global__ __launch_bounds__(256) void k_aggconv(
    const float* __restrict__ bases, const float* __restrict__ comb,
    const float* __restrict__ dinv, const int* __restrict__ rowp,
    const int* __restrict__ col, const float* __restrict__ colw,
    const float* __restrict__ convB,
    float* __restrict__ c1_mem, float* __restrict__ c1_spk) {
  __shared__ float aggl[4][64];
  __shared__ float combl[4][32];
  int w = threadIdx.x >> 6;
  int m = threadIdx.x & 63;
  int d = blockIdx.x * 4 + w;
  float dd = dinv[d];
  int r0 = rowp[d], r1 = rowp[d + 1];
  float acc = 0.f;
  for (int r = r0; r < r1; ++r) {
    int s = col[r];
    float ew  = __fmul_rn(colw[r], dd);
    float upd = __fmul_rn(ew, bases[(size_t)s * 64 + m]);
    acc = __fadd_rn(acc, upd);
  }
  {
    float ew  = __fmul_rn(dd, dd);
    float upd = __fmul_rn(ew, bases[(size_t)d * 64 + m]);
    acc = __fadd_rn(acc, upd);
  }
  aggl[w][m] = acc;
  if (m < 32) combl[w][m] = comb[(size_t)d * 32 + m];
  __syncthreads();
  #pragma unroll
  for (int half = 0; half < 2; ++half) {
    int j = m + half * 64;
    int h = j >> 4, f = j & 15;
    float cv = 0.f;
    #pragma unroll
    for (int b = 0; b < 4; ++b)
      cv = __fadd_rn(cv, __fmul_rn(combl[w][h * 4 + b], aggl[w][b * 16 + f]));
    cv = __fadd_rn(cv, convB[j]);
    int idx = d * 128 + j;
    float cm = c1_mem[idx], cs = c1_spk[idx];
    float nm = __fadd_rn(__fmul_rn(__fmul_rn(cm, 0.2f), __fsub_rn(1.f, cs)), cv);
    c1_mem[idx] = nm;
    c1_spk[idx] = nm > 0.5f ? 1.f : 0.f;
  }
}

// one BLAS panel of the gates GEMM: part[z] = A[:, panel_z] @ B[panel_z, :]
// 512-thread block, same 128x128 tile, 8x4 fragment/thread:
// halves per-thread staging (1 float4 A + 1 float4 B) and acc registers vs 8x8,
// doubling waves/block -> target ~6 waves/SIMD so barrier/load latency hides via TLP.
// Per-output chain: single FMA chain ascending k within the panel (bit-exact,
// identical to the verified 24-panel left-to-right reference chain).
__global__ __launch_bounds__(512) void k_gpanel(
    const float* __restrict__ xl, const float* __restrict__ lh,
    const float* __restrict__ Wih, const float* __restrict__ Whh,
    float* __restrict__ part) {
  __shared__ __align__(16) float Ast[16][132];   // [k][m] transposed
  __shared__ __align__(16) float Bs[16][132];    // [k][n]
  const int tid = threadIdx.x;
  const int tx = tid & 31;              // output col group: cols tx*4..tx*4+3
  const int ty = tid >> 5;              // output row group: rows ty*8..ty*8+7
  const int n0 = blockIdx.x * 128;
  const int m0 = blockIdx.y * 128;
  const int z  = blockIdx.z;

  const float* Asrc; const float* Bsrc; int lda, k0, klen;
  if (z < 22) { Asrc = xl; Bsrc = Wih; lda = 8192; k0 = z * 384; klen = (z == 21) ? 128 : 384; }
  else        { Asrc = lh; Bsrc = Whh; lda = 512;  k0 = (z == 22) ? 0 : 384; klen = (z == 22) ? 384 : 128; }

  float acc[8][4];
  #pragma unroll
  for (int i = 0; i < 8; ++i)
    #pragma unroll
    for (int j = 0; j < 4; ++j) acc[i][j] = 0.f;

  const int arow = tid >> 2;            // 0..127
  const int acol = (tid & 3) * 4;       // 0,4,8,12
  const int brow = tid >> 5;            // 0..15
  const int bcol = (tid & 31) * 4;      // 0..124

  const int nkt = klen >> 4;
  for (int kt = 0; kt < nkt; ++kt) {
    const int kb = k0 + (kt << 4);
    __syncthreads();
    {   // A tile -> transposed LDS (one float4 per thread)
      const float4 va = *(const float4*)(Asrc + (size_t)(m0 + arow) * lda + kb + acol);
      Ast[acol + 0][arow] = va.x; Ast[acol + 1][arow] = va.y;
      Ast[acol + 2][arow] = va.z; Ast[acol + 3][arow] = va.w;
    }
    {   // B tile (one float4 per thread, fully coalesced)
      *(float4*)&Bs[brow][bcol] =
          *(const float4*)(Bsrc + (size_t)(kb + brow) * 2048 + n0 + bcol);
    }
    __syncthreads();
    #pragma unroll
    for (int kk = 0; kk < 16; ++kk) {
      const float4 a0 = *(const float4*)&Ast[kk][ty * 8];
      const float4 a1 = *(const float4*)&Ast[kk][ty * 8 + 4];
      const float4 b0 = *(const float4*)&Bs[kk][tx * 4];
      const float av[8] = {a0.x, a0.y, a0.z, a0.w, a1.x, a1.y, a1.z, a1.w};
      const float bv[4] = {b0.x, b0.y, b0.z, b0.w};
      #pragma unroll
      for (int i = 0; i < 8; ++i)
        #pragma unroll
        for (int j = 0; j < 4; ++j)
          acc[i][j] = __fmaf_rn(av[i], bv[j], acc[i][j]);
    }
  }
  float* dstz = part + (size_t)z * GSTRIDE + (size_t)m0 * 2048 + n0;
  #pragma unroll
  for (int i = 0; i < 8; ++i) {
    const int mr = ty * 8 + i;
    *(float4*)(dstz + (size_t)mr * 2048 + tx * 4) =
        make_float4(acc[i][0], acc[i][1], acc[i][2], acc[i][3]);
  }
}

// combine panel partials strictly left-to-right (matches verified "tih += accP" chain)
__global__ __launch_bounds__(256) void k_combine(
    const float* __restrict__ part, const float* __restrict__ bih,
    const float* __restrict__ bhh, float* __restrict__ gates) {
  const int idx = blockIdx.x * 256 + threadIdx.x;    // m*2048 + u
  const float* p = part + idx;
  float tih = p[0];
  #pragma unroll
  for (int zz = 1; zz < 22; ++zz) tih = __fadd_rn(tih, p[(size_t)zz * GSTRIDE]);
  const float thh = __fadd_rn(p[22u * GSTRIDE], p[23u * GSTRIDE]);
  const int u = idx & 2047;
  gates[idx] = __fadd_rn(__fadd_rn(__fadd_rn(tih, bih[u]), thh), bhh[u]);
}

// fused: gate spikes -> LSTM cell -> fc1 LIF -> fc2 LIF -> h2 accum
__global__ __launch_bounds__(256) void k_cell(
    const float* __restrict__ gates,
    float* __restrict__ lc, float* __restrict__ lh,
    const float* __restrict__ fc1W, const float* __restrict__ fc1b,
    const float* __restrict__ fc2W, const float* __restrict__ fc2b,
    float* __restrict__ h1_mem, float* __restrict__ h1_spk,
    float* __restrict__ h2_mem, float* __restrict__ h2_spk, float* __restrict__ h2_sum) {
  __shared__ float lhl[512];
  __shared__ float sp1l[256];
  const int s = blockIdx.x;
  const int p = threadIdx.x;
  #pragma unroll
  for (int half = 0; half < 2; ++half) {
    const int h = p + half * 256;
    const float giv = gates[(size_t)s * 2048 + h];
    const float gfv = gates[(size_t)s * 2048 + 512 + h];
    const float ggv = gates[(size_t)s * 2048 + 1024 + h];
    const float gov = gates[(size_t)s * 2048 + 1536 + h];
    const float iv = giv > 0.f ? 1.f : 0.f;
    const float fv = gfv > 0.f ? 1.f : 0.f;
    const float gv = ggv > 0.f ? 1.f : 0.f;
    const float ov = gov > 0.f ? 1.f : 0.f;
    const int li = s * 512 + h;
    const float lcv = __fadd_rn(__fmul_rn(fv, lc[li]), __fmul_rn(iv, gv));
    lc[li] = lcv;
    const float lhv = __fmul_rn(lcv, ov);
    lh[li] = lhv;
    lhl[h] = lhv;
  }
  __syncthreads();
  float a0 = 0.f, a1 = 0.f;
  #pragma unroll 8
  for (int q = 0; q < 384; ++q) a0 = __fmaf_rn(lhl[q], fc1W[q * 256 + p], a0);
  #pragma unroll 8
  for (int q = 384; q < 512; ++q) a1 = __fmaf_rn(lhl[q], fc1W[q * 256 + p], a1);
  const float dot1 = __fadd_rn(a0, a1);
  const int i1 = s * 256 + p;
  const float m1 = h1_mem[i1], s1o = h1_spk[i1];
  const float nm1 = __fadd_rn(__fadd_rn(__fmul_rn(__fmul_rn(m1, 0.2f), __fsub_rn(1.f, s1o)), dot1), fc1b[p]);
  h1_mem[i1] = nm1;
  const float sp1 = nm1 > 0.5f ? 1.f : 0.f;
  h1_spk[i1] = sp1;
  sp1l[p] = sp1;
  __syncthreads();
  if (p < 4) {
    float acc = 0.f;
    for (int q = 0; q < 256; ++q) acc = __fmaf_rn(sp1l[q], fc2W[q * 4 + p], acc);
    const int i2 = s * 4 + p;
    const float m2 = h2_mem[i2], s2o = h2_spk[i2];
    const float nm2 = __fadd_rn(__fadd_rn(__fmul_rn(__fmul_rn(m2, 0.2f), __fsub_rn(1.f, s2o)), acc), fc2b[p]);
    h2_mem[i2] = nm2;
    const float sp2 = nm2 > 0.5f ? 1.f : 0.f;
    h2_spk[i2] = sp2;
    h2_sum[i2] = __fadd_rn(h2_sum[i2], sp2);
  }
}

__global__ void k_out(const float* __restrict__ h2_sum, float* __restrict__ out) {
  int i = blockIdx.x * 256 + threadIdx.x;
  if (i < SG * 4) out[i] = __fmul_rn(h2_sum[i], 0.03125f);
}

// ---------------- launch ----------------
extern "C" void kernel_launch(void* const* d_in, const int* in_sizes, int n_in,
                              void* d_out, int out_size, void* d_ws, size_t ws_size,
                              hipStream_t stream) {
  const float* x      = (const float*)d_in[0];
  const int*   ei     = (const int*)  d_in[1];
  const float* encW   = (const float*)d_in[2];
  const float* encB   = (const float*)d_in[3];
  const float* basesW = (const float*)d_in[4];
  const float* basesB = (const float*)d_in[5];
  const float* combW  = (const float*)d_in[6];
  const float* combB  = (const float*)d_in[7];
  const float* convB  = (const float*)d_in[8];
  const float* Wih    = (const float*)d_in[9];
  const float* Whh    = (const float*)d_in[10];
  const float* bih    = (const float*)d_in[11];
  const float* bhh    = (const float*)d_in[12];
  const float* fc1W   = (const float*)d_in[13];
  const float* fc1b   = (const float*)d_in[14];
  const float* fc2W   = (const float*)d_in[15];
  const float* fc2b   = (const float*)d_in[16];

  float* ws = (float*)d_ws;
  float* enc_mem = ws + OFF_ENC_MEM;
  float* enc_spk = ws + OFF_ENC_SPK;
  float* c1_mem  = ws + OFF_C1_MEM;
  float* c1_spk  = ws + OFF_C1_SPK;   // xl
  float* lhp     = ws + OFF_LH;
  float* lcp     = ws + OFF_LC;
  float* h1_mem  = ws + OFF_H1_MEM;
  float* h1_spk  = ws + OFF_H1_SPK;
  float* h2_mem  = ws + OFF_H2_MEM;
  float* h2_spk  = ws + OFF_H2_SPK;
  float* h2_sum  = ws + OFF_H2_SUM;
  float* bases   = ws + OFF_BASES;
  float* comb    = ws + OFF_COMB;
  float* gates   = ws + OFF_GATES;
  float* partp   = ws + OFF_PART;
  float* dinv    = ws + OFF_DINV;
  float* colw    = ws + OFF_COLW;
  int* ibase = (int*)((char*)d_ws + (size_t)FLOAT_END * 4);
  int* deg  = ibase + IOFF_DEG;
  int* fill = ibase + IOFF_FILL;
  int* rowp = ibase + IOFF_ROWPTR;
  int* eid  = ibase + IOFF_EID;
  int* col  = ibase + IOFF_COL;

  hipMemsetAsync(ws, 0, (size_t)ZERO_FLOATS * 4, stream);
  hipMemsetAsync(ibase, 0, 32768 * 4, stream);

  k_deg    <<<NE / 256, 256, 0, stream>>>(ei, deg);
  k_dinv   <<<NN / 256, 256, 0, stream>>>(deg, dinv);
  k_scan   <<<1, 1024, 0, stream>>>(deg, rowp);
  k_scatter<<<NE / 256, 256, 0, stream>>>(ei, rowp, fill, eid);
  k_sortadj<<<NN / 256, 256, 0, stream>>>(rowp, eid, ei, dinv, col, colw);

  for (int t = 0; t < TSTEPS; ++t) {
    k_bases_comb<<<NN / 64, 256, 0, stream>>>(x, encW, encB, enc_mem, enc_spk,
                                              basesW, basesB, combW, combB, bases, comb, t);
    k_aggconv   <<<NN / 4, 256, 0, stream>>>(bases, comb, dinv, rowp, col, colw, convB, c1_mem, c1_spk);
    k_gpanel    <<<dim3(16, 2, NPANEL), 512, 0, stream>>>(c1_spk, lhp, Wih, Whh, partp);
    k_combine   <<<2048, 256, 0, stream>>>(partp, bih, bhh, gates);
    k_cell      <<<SG, 256, 0, stream>>>(gates, lcp, lhp, fc1W, fc1b, fc2W, fc2b,
                                         h1_mem, h1_spk, h2_mem, h2_spk, h2_sum);
  }
  k_out<<<4, 256, 0, stream>>>(h2_sum, (float*)d_out);
}

// Round 6
// 6908.601 us; speedup vs baseline: 8.6018x; 1.0039x over previous
//
#include <hip/hip_runtime.h>

// ---------------- problem constants ----------------
#define NN      16384      // total nodes
#define TSTEPS  32
#define SG      256        // graphs
#define NE      262144
#define NPANEL  24         // 22 panels for xl@Wih (21x384 + 128) + 2 for lh@Whh (384+128)
#define GSTRIDE 524288u    // 256*2048 floats per panel partial

// ---------------- workspace layout (float offsets) ----------------
#define OFF_ENC_MEM   0u
#define OFF_ENC_SPK   2097152u
#define OFF_C1_MEM    4194304u
#define OFF_C1_SPK    6291456u     // == xl [256][8192]
#define OFF_LH        8388608u
#define OFF_LC        8519680u
#define OFF_H1_MEM    8650752u
#define OFF_H1_SPK    8716288u
#define OFF_H2_MEM    8781824u
#define OFF_H2_SPK    8782848u
#define OFF_H2_SUM    8783872u
#define ZERO_FLOATS   8784896u     // everything below here zeroed each launch
#define OFF_BASES     8784896u
#define OFF_COMB      9833472u
#define OFF_GATES     10357760u    // 256 x 2048
#define OFF_PART      10882048u    // 24 x 256 x 2048 panel partials
#define OFF_DINV      23464960u
#define OFF_COLW      23481344u
#define FLOAT_END     23743488u
// int region (offsets from ibase)
#define IOFF_DEG      0
#define IOFF_FILL     16384
#define IOFF_ROWPTR   32768
#define IOFF_EID      49153
#define IOFF_COL      311297
#define INT_COUNT     573441

// ---------------- graph preprocessing ----------------
__global__ void k_deg(const int* __restrict__ ei, int* __restrict__ deg) {
  int e = blockIdx.x * 256 + threadIdx.x;
  if (e < NE) atomicAdd(&deg[ei[NE + e]], 1);
}

__global__ void k_dinv(const int* __restrict__ deg, float* __restrict__ dinv) {
  int n = blockIdx.x * 256 + threadIdx.x;
  if (n < NN) dinv[n] = __fdiv_rn(1.0f, __fsqrt_rn((float)(deg[n] + 1)));  // +1 self-loop
}

__global__ void k_scan(const int* __restrict__ deg, int* __restrict__ rowp) {
  __shared__ int sdata[1024];
  int tid = threadIdx.x;
  int base = tid * 16;
  int loc[16];
  int sum = 0;
  #pragma unroll
  for (int i = 0; i < 16; ++i) { loc[i] = sum; sum += deg[base + i]; }
  sdata[tid] = sum;
  __syncthreads();
  for (int off = 1; off < 1024; off <<= 1) {
    int v = 0;
    if (tid >= off) v = sdata[tid - off];
    __syncthreads();
    sdata[tid] += v;
    __syncthreads();
  }
  int excl = (tid == 0) ? 0 : sdata[tid - 1];
  #pragma unroll
  for (int i = 0; i < 16; ++i) rowp[base + i] = excl + loc[i];
  if (tid == 1023) rowp[NN] = sdata[1023];
}

__global__ void k_scatter(const int* __restrict__ ei, const int* __restrict__ rowp,
                          int* __restrict__ fill, int* __restrict__ eid) {
  int e = blockIdx.x * 256 + threadIdx.x;
  if (e >= NE) return;
  int d = ei[NE + e];
  int pos = rowp[d] + atomicAdd(&fill[d], 1);
  eid[pos] = e;
}

// sort each adjacency list by EDGE ID (unique keys) -> summation order == scatter-add order
__global__ void k_sortadj(const int* __restrict__ rowp, int* __restrict__ eid,
                          const int* __restrict__ ei, const float* __restrict__ dinv,
                          int* __restrict__ col, float* __restrict__ colw) {
  int d = blockIdx.x * 256 + threadIdx.x;
  if (d >= NN) return;
  int r0 = rowp[d], r1 = rowp[d + 1];
  for (int i = r0 + 1; i < r1; ++i) {
    int key = eid[i];
    int j = i - 1;
    while (j >= r0 && eid[j] > key) { eid[j + 1] = eid[j]; --j; }
    eid[j + 1] = key;
  }
  for (int i = r0; i < r1; ++i) {
    int s = ei[eid[i]];
    col[i] = s;
    colw[i] = dinv[s];
  }
}

// ---------------- per-timestep kernels ----------------
// FUSED: enc LIF (in-block, 64 nodes) -> bases/comb GEMMs.
// enc chain identical to old k_enc: dot ascending c, then LIF update, spike.
__global__ __launch_bounds__(256) void k_bases_comb(
    const float* __restrict__ x, const float* __restrict__ encW, const float* __restrict__ encB,
    float* __restrict__ enc_mem, float* __restrict__ enc_spk,
    const float* __restrict__ basesW, const float* __restrict__ basesB,
    const float* __restrict__ combW, const float* __restrict__ combB,
    float* __restrict__ bases, float* __restrict__ comb, int t) {
  __shared__ float xs[64][8];      // staged inputs for this block's 64 nodes
  __shared__ float sp[64 * 129];   // [node][j], pad 129 -> (n+j)%32 banks
  __shared__ float ob[64 * 65];    // bases out [node][ch], pad 65
  __shared__ float oc[64 * 33];    // comb out [node][ch], pad 33
  const int tid = threadIdx.x;
  const int nb = blockIdx.x * 64;
  // stage x: 64 nodes x 8 channels
  #pragma unroll
  for (int k = 0; k < 2; ++k) {
    int idx = k * 256 + tid;
    int n = idx >> 3, c = idx & 7;
    xs[n][c] = x[(size_t)(nb + n) * 256 + (size_t)c * 32 + t];
  }
  __syncthreads();
  // enc LIF for this block's 64 nodes (identical op chain to old k_enc)
  #pragma unroll 4
  for (int k = 0; k < 32; ++k) {
    int idx = k * 256 + tid;
    int n = idx >> 7, j = idx & 127;   // n uniform per wave -> xs broadcast reads
    int gidx = nb * 128 + idx;
    float dot = 0.f;
    #pragma unroll
    for (int c = 0; c < 8; ++c) dot = __fmaf_rn(xs[n][c], encW[c * 128 + j], dot);
    float m = enc_mem[gidx], s = enc_spk[gidx];
    float nm = __fadd_rn(__fadd_rn(__fmul_rn(__fmul_rn(m, 0.2f), __fsub_rn(1.f, s)), dot), encB[j]);
    enc_mem[gidx] = nm;
    float spk = nm > 0.5f ? 1.f : 0.f;
    enc_spk[gidx] = spk;
    sp[n * 129 + j] = spk;
  }
  __syncthreads();
  const int lane = tid & 63;
  const int w = tid >> 6;
  const float* spn = sp + lane * 129;
  if (w < 2) {
    const int ch0 = w * 32;
    const float* Wp = basesW + ch0;
    float acc[32];
    #pragma unroll
    for (int c = 0; c < 32; ++c) acc[c] = 0.f;
    for (int j = 0; j < 128; ++j) {
      const float s = spn[j];
      const float* wr = Wp + j * 64;     // lane-invariant -> scalar loads
      #pragma unroll
      for (int c = 0; c < 32; ++c) acc[c] = __fmaf_rn(s, wr[c], acc[c]);
    }
    #pragma unroll
    for (int c = 0; c < 32; ++c) ob[lane * 65 + ch0 + c] = acc[c];
  } else {
    const int ch0 = (w - 2) * 16;
    const float* Wp = combW + ch0;
    float acc[16];
    #pragma unroll
    for (int c = 0; c < 16; ++c) acc[c] = 0.f;
    for (int j = 0; j < 128; ++j) {
      const float s = spn[j];
      const float* wr = Wp + j * 32;
      #pragma unroll
      for (int c = 0; c < 16; ++c) acc[c] = __fmaf_rn(s, wr[c], acc[c]);
    }
    #pragma unroll
    for (int c = 0; c < 16; ++c) oc[lane * 33 + ch0 + c] = acc[c];
  }
  __syncthreads();
  // coalesced stores with bias
  #pragma unroll
  for (int r = 0; r < 16; ++r) {
    int idx = r * 256 + tid;
    int n = idx >> 6, ch = idx & 63;
    bases[(size_t)(nb + n) * 64 + ch] = __fadd_rn(ob[n * 65 + ch], basesB[ch]);
  }
  #pragma unroll
  for (int r = 0; r < 8; ++r) {
    int idx = r * 256 + tid;
    int n = idx >> 5, ch = idx & 31;
    comb[(size_t)(nb + n) * 32 + ch] = __fadd_rn(oc[n * 33 + ch], combB[ch]);
  }
}

// fused: symnorm aggregation (edge-order scatter-add) -> einsum -> conv LIF -> c1 spike
__global__ __launch_bounds__(256) void k_aggconv(
    const float* __restrict__ bases, const float* __restrict__ comb,
    const float* __restrict__ dinv, const int* __restrict__ rowp,
    const int* __restrict__ col, const float* __restrict__ colw,
    const float* __restrict__ convB,
    float* __restrict__ c1_mem, float* __restrict__ c1_spk) {
  __shared__ float aggl[4][64];
  __shared__ float combl[4][32];
  int w = threadIdx.x >> 6;
  int m = threadIdx.x & 63;
  int d = blockIdx.x * 4 + w;
  float dd = dinv[d];
  int r0 = rowp[d], r1 = rowp[d + 1];
  float acc = 0.f;
  for (int r = r0; r < r1; ++r) {
    int s = col[r];
    float ew  = __fmul_rn(colw[r], dd);
    float upd = __fmul_rn(ew, bases[(size_t)s * 64 + m]);
    acc = __fadd_rn(acc, upd);
  }
  {
    float ew  = __fmul_rn(dd, dd);
    float upd = __fmul_rn(ew, bases[(size_t)d * 64 + m]);
    acc = __fadd_rn(acc, upd);
  }
  aggl[w][m] = acc;
  if (m < 32) combl[w][m] = comb[(size_t)d * 32 + m];
  __syncthreads();
  #pragma unroll
  for (int half = 0; half < 2; ++half) {
    int j = m + half * 64;
    int h = j >> 4, f = j & 15;
    float cv = 0.f;
    #pragma unroll
    for (int b = 0; b < 4; ++b)
      cv = __fadd_rn(cv, __fmul_rn(combl[w][h * 4 + b], aggl[w][b * 16 + f]));
    cv = __fadd_rn(cv, convB[j]);
    int idx = d * 128 + j;
    float cm = c1_mem[idx], cs = c1_spk[idx];
    float nm = __fadd_rn(__fmul_rn(__fmul_rn(cm, 0.2f), __fsub_rn(1.f, cs)), cv);
    c1_mem[idx] = nm;
    c1_spk[idx] = nm > 0.5f ? 1.f : 0.f;
  }
}

// one BLAS panel of the gates GEMM: part[z] = A[:, panel_z] @ B[panel_z, :]
// 512 threads, 128x128 tile, 8x4 frag (R5 shape: measured 36 VGPR, no spill)
// + double-buffered LDS, ONE barrier per K-tile. Staging = 2 float4/thread only.
// Order per iter: issue next loads -> compute cur buf -> write regs to alt buf -> barrier.
// Alt-buf write is safe: all waves finished reading it before the PREVIOUS barrier.
// Per-output chain: single FMA chain ascending k (kt asc, kk asc) - bit-exact.
__global__ __launch_bounds__(512) void k_gpanel(
    const float* __restrict__ xl, const float* __restrict__ lh,
    const float* __restrict__ Wih, const float* __restrict__ Whh,
    float* __restrict__ part) {
  __shared__ __align__(16) float Ast[2][16][132];   // [buf][k][m] transposed
  __shared__ __align__(16) float Bs[2][16][132];    // [buf][k][n]
  const int tid = threadIdx.x;
  const int tx = tid & 31;              // output cols tx*4..tx*4+3
  const int ty = tid >> 5;              // output rows ty*8..ty*8+7
  const int n0 = blockIdx.x * 128;
  const int m0 = blockIdx.y * 128;
  const int z  = blockIdx.z;

  const float* Asrc; const float* Bsrc; int lda, k0, klen;
  if (z < 22) { Asrc = xl; Bsrc = Wih; lda = 8192; k0 = z * 384; klen = (z == 21) ? 128 : 384; }
  else        { Asrc = lh; Bsrc = Whh; lda = 512;  k0 = (z == 22) ? 0 : 384; klen = (z == 22) ? 384 : 128; }

  float acc[8][4];
  #pragma unroll
  for (int i = 0; i < 8; ++i)
    #pragma unroll
    for (int j = 0; j < 4; ++j) acc[i][j] = 0.f;

  const int arow = tid >> 2;            // 0..127
  const int acol = (tid & 3) * 4;       // 0,4,8,12
  const int brow = tid >> 5;            // 0..15
  const int bcol = (tid & 31) * 4;      // 0..124

  const int nkt = klen >> 4;

  float4 va, vb;                        // 8 staging VGPRs

  // prologue: tile 0 -> buf 0
  va = *(const float4*)(Asrc + (size_t)(m0 + arow) * lda + k0 + acol);
  vb = *(const float4*)(Bsrc + (size_t)(k0 + brow) * 2048 + n0 + bcol);
  Ast[0][acol + 0][arow] = va.x; Ast[0][acol + 1][arow] = va.y;
  Ast[0][acol + 2][arow] = va.z; Ast[0][acol + 3][arow] = va.w;
  *(float4*)&Bs[0][brow][bcol] = vb;
  __syncthreads();

  for (int kt = 0; kt < nkt; ++kt) {
    const int cur = kt & 1;
    const bool more = (kt + 1 < nkt);
    if (more) {   // issue next-tile loads; latency hides under compute
      const int kb = k0 + ((kt + 1) << 4);
      va = *(const float4*)(Asrc + (size_t)(m0 + arow) * lda + kb + acol);
      vb = *(const float4*)(Bsrc + (size_t)(kb + brow) * 2048 + n0 + bcol);
    }
    #pragma unroll
    for (int kk = 0; kk < 16; ++kk) {
      const float4 a0 = *(const float4*)&Ast[cur][kk][ty * 8];
      const float4 a1 = *(const float4*)&Ast[cur][kk][ty * 8 + 4];
      const float4 b0 = *(const float4*)&Bs[cur][kk][tx * 4];
      const float av[8] = {a0.x, a0.y, a0.z, a0.w, a1.x, a1.y, a1.z, a1.w};
      const float bv[4] = {b0.x, b0.y, b0.z, b0.w};
      #pragma unroll
      for (int i = 0; i < 8; ++i)
        #pragma unroll
        for (int j = 0; j < 4; ++j)
          acc[i][j] = __fmaf_rn(av[i], bv[j], acc[i][j]);
    }
    if (more) {
      const int nxt = cur ^ 1;
      Ast[nxt][acol + 0][arow] = va.x; Ast[nxt][acol + 1][arow] = va.y;
      Ast[nxt][acol + 2][arow] = va.z; Ast[nxt][acol + 3][arow] = va.w;
      *(float4*)&Bs[nxt][brow][bcol] = vb;
      __syncthreads();
    }
  }

  float* dstz = part + (size_t)z * GSTRIDE + (size_t)m0 * 2048 + n0;
  #pragma unroll
  for (int i = 0; i < 8; ++i) {
    const int mr = ty * 8 + i;
    *(float4*)(dstz + (size_t)mr * 2048 + tx * 4) =
        make_float4(acc[i][0], acc[i][1], acc[i][2], acc[i][3]);
  }
}

// combine panel partials strictly left-to-right (matches verified "tih += accP" chain)
__global__ __launch_bounds__(256) void k_combine(
    const float* __restrict__ part, const float* __restrict__ bih,
    const float* __restrict__ bhh, float* __restrict__ gates) {
  const int idx = blockIdx.x * 256 + threadIdx.x;    // m*2048 + u
  const float* p = part + idx;
  float tih = p[0];
  #pragma unroll
  for (int zz = 1; zz < 22; ++zz) tih = __fadd_rn(tih, p[(size_t)zz * GSTRIDE]);
  const float thh = __fadd_rn(p[22u * GSTRIDE], p[23u * GSTRIDE]);
  const int u = idx & 2047;
  gates[idx] = __fadd_rn(__fadd_rn(__fadd_rn(tih, bih[u]), thh), bhh[u]);
}

// fused: gate spikes -> LSTM cell -> fc1 LIF -> fc2 LIF -> h2 accum
__global__ __launch_bounds__(256) void k_cell(
    const float* __restrict__ gates,
    float* __restrict__ lc, float* __restrict__ lh,
    const float* __restrict__ fc1W, const float* __restrict__ fc1b,
    const float* __restrict__ fc2W, const float* __restrict__ fc2b,
    float* __restrict__ h1_mem, float* __restrict__ h1_spk,
    float* __restrict__ h2_mem, float* __restrict__ h2_spk, float* __restrict__ h2_sum) {
  __shared__ float lhl[512];
  __shared__ float sp1l[256];
  const int s = blockIdx.x;
  const int p = threadIdx.x;
  #pragma unroll
  for (int half = 0; half < 2; ++half) {
    const int h = p + half * 256;
    const float giv = gates[(size_t)s * 2048 + h];
    const float gfv = gates[(size_t)s * 2048 + 512 + h];
    const float ggv = gates[(size_t)s * 2048 + 1024 + h];
    const float gov = gates[(size_t)s * 2048 + 1536 + h];
    const float iv = giv > 0.f ? 1.f : 0.f;
    const float fv = gfv > 0.f ? 1.f : 0.f;
    const float gv = ggv > 0.f ? 1.f : 0.f;
    const float ov = gov > 0.f ? 1.f : 0.f;
    const int li = s * 512 + h;
    const float lcv = __fadd_rn(__fmul_rn(fv, lc[li]), __fmul_rn(iv, gv));
    lc[li] = lcv;
    const float lhv = __fmul_rn(lcv, ov);
    lh[li] = lhv;
    lhl[h] = lhv;
  }
  __syncthreads();
  float a0 = 0.f, a1 = 0.f;
  #pragma unroll 8
  for (int q = 0; q < 384; ++q) a0 = __fmaf_rn(lhl[q], fc1W[q * 256 + p], a0);
  #pragma unroll 8
  for (int q = 384; q < 512; ++q) a1 = __fmaf_rn(lhl[q], fc1W[q * 256 + p], a1);
  const float dot1 = __fadd_rn(a0, a1);
  const int i1 = s * 256 + p;
  const float m1 = h1_mem[i1], s1o = h1_spk[i1];
  const float nm1 = __fadd_rn(__fadd_rn(__fmul_rn(__fmul_rn(m1, 0.2f), __fsub_rn(1.f, s1o)), dot1), fc1b[p]);
  h1_mem[i1] = nm1;
  const float sp1 = nm1 > 0.5f ? 1.f : 0.f;
  h1_spk[i1] = sp1;
  sp1l[p] = sp1;
  __syncthreads();
  if (p < 4) {
    float acc = 0.f;
    for (int q = 0; q < 256; ++q) acc = __fmaf_rn(sp1l[q], fc2W[q * 4 + p], acc);
    const int i2 = s * 4 + p;
    const float m2 = h2_mem[i2], s2o = h2_spk[i2];
    const float nm2 = __fadd_rn(__fadd_rn(__fmul_rn(__fmul_rn(m2, 0.2f), __fsub_rn(1.f, s2o)), acc), fc2b[p]);
    h2_mem[i2] = nm2;
    const float sp2 = nm2 > 0.5f ? 1.f : 0.f;
    h2_spk[i2] = sp2;
    h2_sum[i2] = __fadd_rn(h2_sum[i2], sp2);
  }
}

__global__ void k_out(const float* __restrict__ h2_sum, float* __restrict__ out) {
  int i = blockIdx.x * 256 + threadIdx.x;
  if (i < SG * 4) out[i] = __fmul_rn(h2_sum[i], 0.03125f);
}

// ---------------- launch ----------------
extern "C" void kernel_launch(void* const* d_in, const int* in_sizes, int n_in,
                              void* d_out, int out_size, void* d_ws, size_t ws_size,
                              hipStream_t stream) {
  const float* x      = (const float*)d_in[0];
  const int*   ei     = (const int*)  d_in[1];
  const float* encW   = (const float*)d_in[2];
  const float* encB   = (const float*)d_in[3];
  const float* basesW = (const float*)d_in[4];
  const float* basesB = (const float*)d_in[5];
  const float* combW  = (const float*)d_in[6];
  const float* combB  = (const float*)d_in[7];
  const float* convB  = (const float*)d_in[8];
  const float* Wih    = (const float*)d_in[9];
  const float* Whh    = (const float*)d_in[10];
  const float* bih    = (const float*)d_in[11];
  const float* bhh    = (const float*)d_in[12];
  const float* fc1W   = (const float*)d_in[13];
  const float* fc1b   = (const float*)d_in[14];
  const float* fc2W   = (const float*)d_in[15];
  const float* fc2b   = (const float*)d_in[16];

  float* ws = (float*)d_ws;
  float* enc_mem = ws + OFF_ENC_MEM;
  float* enc_spk = ws + OFF_ENC_SPK;
  float* c1_mem  = ws + OFF_C1_MEM;
  float* c1_spk  = ws + OFF_C1_SPK;   // xl
  float* lhp     = ws + OFF_LH;
  float* lcp     = ws + OFF_LC;
  float* h1_mem  = ws + OFF_H1_MEM;
  float* h1_spk  = ws + OFF_H1_SPK;
  float* h2_mem  = ws + OFF_H2_MEM;
  float* h2_spk  = ws + OFF_H2_SPK;
  float* h2_sum  = ws + OFF_H2_SUM;
  float* bases   = ws + OFF_BASES;
  float* comb    = ws + OFF_COMB;
  float* gates   = ws + OFF_GATES;
  float* partp   = ws + OFF_PART;
  float* dinv    = ws + OFF_DINV;
  float* colw    = ws + OFF_COLW;
  int* ibase = (int*)((char*)d_ws + (size_t)FLOAT_END * 4);
  int* deg  = ibase + IOFF_DEG;
  int* fill = ibase + IOFF_FILL;
  int* rowp = ibase + IOFF_ROWPTR;
  int* eid  = ibase + IOFF_EID;
  int* col  = ibase + IOFF_COL;

  hipMemsetAsync(ws, 0, (size_t)ZERO_FLOATS * 4, stream);
  hipMemsetAsync(ibase, 0, 32768 * 4, stream);

  k_deg    <<<NE / 256, 256, 0, stream>>>(ei, deg);
  k_dinv   <<<NN / 256, 256, 0, stream>>>(deg, dinv);
  k_scan   <<<1, 1024, 0, stream>>>(deg, rowp);
  k_scatter<<<NE / 256, 256, 0, stream>>>(ei, rowp, fill, eid);
  k_sortadj<<<NN / 256, 256, 0, stream>>>(rowp, eid, ei, dinv, col, colw);

  for (int t = 0; t < TSTEPS; ++t) {
    k_bases_comb<<<NN / 64, 256, 0, stream>>>(x, encW, encB, enc_mem, enc_spk,
                                              basesW, basesB, combW, combB, bases, comb, t);
    k_aggconv   <<<NN / 4, 256, 0, stream>>>(bases, comb, dinv, rowp, col, colw, convB, c1_mem, c1_spk);
    k_gpanel    <<<dim3(16, 2, NPANEL), 512, 0, stream>>>(c1_spk, lhp, Wih, Whh, partp);
    k_combine   <<<2048, 256, 0, stream>>>(partp, bih, bhh, gates);
    k_cell      <<<SG, 256, 0, stream>>>(gates, lcp, lhp, fc1W, fc1b, fc2W, fc2b,
                                         h1_mem, h1_spk, h2_mem, h2_spk, h2_sum);
  }
  k_out<<<4, 256, 0, stream>>>(h2_sum, (float*)d_out);
}

// Round 8
// 6122.412 us; speedup vs baseline: 9.7064x; 1.1284x over previous
//
#include <hip/hip_runtime.h>

// ---------------- problem constants ----------------
#define NN      16384      // total nodes
#define TSTEPS  32
#define SG      256        // graphs
#define NE      262144
#define NPANEL  24         // 22 panels for xl@Wih (21x384 + 128) + 2 for lh@Whh (384+128)
#define GSTRIDE 524288u    // 256*2048 floats per panel partial

// ---------------- workspace layout (float offsets) ----------------
#define OFF_ENC_MEM   0u
#define OFF_ENC_SPK   2097152u
#define OFF_C1_MEM    4194304u
#define OFF_C1_SPK    6291456u     // == xl [256][8192]
#define OFF_LH        8388608u
#define OFF_LC        8519680u
#define OFF_H1_MEM    8650752u
#define OFF_H1_SPK    8716288u
#define OFF_H2_MEM    8781824u
#define OFF_H2_SPK    8782848u
#define OFF_H2_SUM    8783872u
#define ZERO_FLOATS   8784896u     // everything below here zeroed each launch
#define OFF_BASES     8784896u
#define OFF_COMB      9833472u
#define OFF_GATES     10357760u    // 256 x 2048
#define OFF_PART      10882048u    // 24 x 256 x 2048 panel partials
#define OFF_DINV      23464960u
#define OFF_COLW      23481344u
#define FLOAT_END     23743488u
// int region (offsets from ibase)
#define IOFF_DEG      0
#define IOFF_FILL     16384
#define IOFF_ROWPTR   32768
#define IOFF_EID      49153
#define IOFF_COL      311297
#define INT_COUNT     573441

// ---------------- graph preprocessing ----------------
__global__ void k_deg(const int* __restrict__ ei, int* __restrict__ deg) {
  int e = blockIdx.x * 256 + threadIdx.x;
  if (e < NE) atomicAdd(&deg[ei[NE + e]], 1);
}

__global__ void k_dinv(const int* __restrict__ deg, float* __restrict__ dinv) {
  int n = blockIdx.x * 256 + threadIdx.x;
  if (n < NN) dinv[n] = __fdiv_rn(1.0f, __fsqrt_rn((float)(deg[n] + 1)));  // +1 self-loop
}

__global__ void k_scan(const int* __restrict__ deg, int* __restrict__ rowp) {
  __shared__ int sdata[1024];
  int tid = threadIdx.x;
  int base = tid * 16;
  int loc[16];
  int sum = 0;
  #pragma unroll
  for (int i = 0; i < 16; ++i) { loc[i] = sum; sum += deg[base + i]; }
  sdata[tid] = sum;
  __syncthreads();
  for (int off = 1; off < 1024; off <<= 1) {
    int v = 0;
    if (tid >= off) v = sdata[tid - off];
    __syncthreads();
    sdata[tid] += v;
    __syncthreads();
  }
  int excl = (tid == 0) ? 0 : sdata[tid - 1];
  #pragma unroll
  for (int i = 0; i < 16; ++i) rowp[base + i] = excl + loc[i];
  if (tid == 1023) rowp[NN] = sdata[1023];
}

__global__ void k_scatter(const int* __restrict__ ei, const int* __restrict__ rowp,
                          int* __restrict__ fill, int* __restrict__ eid) {
  int e = blockIdx.x * 256 + threadIdx.x;
  if (e >= NE) return;
  int d = ei[NE + e];
  int pos = rowp[d] + atomicAdd(&fill[d], 1);
  eid[pos] = e;
}

// sort each adjacency list by EDGE ID (unique keys) -> summation order == scatter-add order
__global__ void k_sortadj(const int* __restrict__ rowp, int* __restrict__ eid,
                          const int* __restrict__ ei, const float* __restrict__ dinv,
                          int* __restrict__ col, float* __restrict__ colw) {
  int d = blockIdx.x * 256 + threadIdx.x;
  if (d >= NN) return;
  int r0 = rowp[d], r1 = rowp[d + 1];
  for (int i = r0 + 1; i < r1; ++i) {
    int key = eid[i];
    int j = i - 1;
    while (j >= r0 && eid[j] > key) { eid[j + 1] = eid[j]; --j; }
    eid[j + 1] = key;
  }
  for (int i = r0; i < r1; ++i) {
    int s = ei[eid[i]];
    col[i] = s;
    colw[i] = dinv[s];
  }
}

// ---------------- per-timestep kernels ----------------
// FUSED: enc LIF (in-block, 64 nodes) -> bases/comb GEMMs. 512 threads:
// 8 wave-roles (w0-3 bases 16ch, w4-7 comb 8ch) -> 2 waves/SIMD during the
// j-loop (was 1/SIMD at 256 thr). Per-(lane,ch) FMA chain identical (j asc).
__global__ __launch_bounds__(512) void k_bases_comb(
    const float* __restrict__ x, const float* __restrict__ encW, const float* __restrict__ encB,
    float* __restrict__ enc_mem, float* __restrict__ enc_spk,
    const float* __restrict__ basesW, const float* __restrict__ basesB,
    const float* __restrict__ combW, const float* __restrict__ combB,
    float* __restrict__ bases, float* __restrict__ comb, int t) {
  __shared__ float xs[64][8];      // staged inputs for this block's 64 nodes
  __shared__ float sp[64 * 129];   // [node][j], pad 129 -> (n+j)%32 banks
  __shared__ float ob[64 * 65];    // bases out [node][ch], pad 65
  __shared__ float oc[64 * 33];    // comb out [node][ch], pad 33
  const int tid = threadIdx.x;
  const int nb = blockIdx.x * 64;
  // stage x: 64 nodes x 8 channels (one element per thread)
  {
    int n = tid >> 3, c = tid & 7;
    xs[n][c] = x[(size_t)(nb + n) * 256 + (size_t)c * 32 + t];
  }
  __syncthreads();
  // enc LIF for this block's 64 nodes (identical op chain to old k_enc)
  #pragma unroll 4
  for (int k = 0; k < 16; ++k) {
    int idx = k * 512 + tid;
    int n = idx >> 7, j = idx & 127;   // n uniform per wave -> xs broadcast reads
    int gidx = nb * 128 + idx;
    float dot = 0.f;
    #pragma unroll
    for (int c = 0; c < 8; ++c) dot = __fmaf_rn(xs[n][c], encW[c * 128 + j], dot);
    float m = enc_mem[gidx], s = enc_spk[gidx];
    float nm = __fadd_rn(__fadd_rn(__fmul_rn(__fmul_rn(m, 0.2f), __fsub_rn(1.f, s)), dot), encB[j]);
    enc_mem[gidx] = nm;
    float spk = nm > 0.5f ? 1.f : 0.f;
    enc_spk[gidx] = spk;
    sp[n * 129 + j] = spk;
  }
  __syncthreads();
  const int lane = tid & 63;
  const int w = tid >> 6;              // 0..7
  const float* spn = sp + lane * 129;
  if (w < 4) {
    const int ch0 = w * 16;
    const float* Wp = basesW + ch0;
    float acc[16];
    #pragma unroll
    for (int c = 0; c < 16; ++c) acc[c] = 0.f;
    for (int j = 0; j < 128; ++j) {
      const float s = spn[j];
      const float* wr = Wp + j * 64;     // lane-invariant -> scalar loads
      #pragma unroll
      for (int c = 0; c < 16; ++c) acc[c] = __fmaf_rn(s, wr[c], acc[c]);
    }
    #pragma unroll
    for (int c = 0; c < 16; ++c) ob[lane * 65 + ch0 + c] = acc[c];
  } else {
    const int ch0 = (w - 4) * 8;
    const float* Wp = combW + ch0;
    float acc[8];
    #pragma unroll
    for (int c = 0; c < 8; ++c) acc[c] = 0.f;
    for (int j = 0; j < 128; ++j) {
      const float s = spn[j];
      const float* wr = Wp + j * 32;
      #pragma unroll
      for (int c = 0; c < 8; ++c) acc[c] = __fmaf_rn(s, wr[c], acc[c]);
    }
    #pragma unroll
    for (int c = 0; c < 8; ++c) oc[lane * 33 + ch0 + c] = acc[c];
  }
  __syncthreads();
  // coalesced stores with bias
  #pragma unroll
  for (int r = 0; r < 8; ++r) {
    int idx = r * 512 + tid;
    int n = idx >> 6, ch = idx & 63;
    bases[(size_t)(nb + n) * 64 + ch] = __fadd_rn(ob[n * 65 + ch], basesB[ch]);
  }
  #pragma unroll
  for (int r = 0; r < 4; ++r) {
    int idx = r * 512 + tid;
    int n = idx >> 5, ch = idx & 31;
    comb[(size_t)(nb + n) * 32 + ch] = __fadd_rn(oc[n * 33 + ch], combB[ch]);
  }
}

// fused: symnorm aggregation (edge-order scatter-add) -> einsum -> conv LIF -> c1 spike
// gather loop unrolled x4: col/colw/bases loads hoisted ahead of the ordered fadds
// (4-deep MLP on the col->bases dependent chain; fadd order unchanged -> bit-exact).
__global__ __launch_bounds__(256) void k_aggconv(
    const float* __restrict__ bases, const float* __restrict__ comb,
    const float* __restrict__ dinv, const int* __restrict__ rowp,
    const int* __restrict__ col, const float* __restrict__ colw,
    const float* __restrict__ convB,
    float* __restrict__ c1_mem, float* __restrict__ c1_spk) {
  __shared__ float aggl[4][64];
  __shared__ float combl[4][32];
  int w = threadIdx.x >> 6;
  int m = threadIdx.x & 63;
  int d = blockIdx.x * 4 + w;
  float dd = dinv[d];
  int r0 = rowp[d], r1 = rowp[d + 1];
  float acc = 0.f;
  int r = r0;
  for (; r + 4 <= r1; r += 4) {
    const int s0 = col[r], s1 = col[r + 1], s2 = col[r + 2], s3 = col[r + 3];
    const float w0 = colw[r], w1 = colw[r + 1], w2 = colw[r + 2], w3 = colw[r + 3];
    const float b0 = bases[(size_t)s0 * 64 + m];
    const float b1 = bases[(size_t)s1 * 64 + m];
    const float b2 = bases[(size_t)s2 * 64 + m];
    const float b3 = bases[(size_t)s3 * 64 + m];
    acc = __fadd_rn(acc, __fmul_rn(__fmul_rn(w0, dd), b0));
    acc = __fadd_rn(acc, __fmul_rn(__fmul_rn(w1, dd), b1));
    acc = __fadd_rn(acc, __fmul_rn(__fmul_rn(w2, dd), b2));
    acc = __fadd_rn(acc, __fmul_rn(__fmul_rn(w3, dd), b3));
  }
  for (; r < r1; ++r) {
    int s = col[r];
    float ew  = __fmul_rn(colw[r], dd);
    float upd = __fmul_rn(ew, bases[(size_t)s * 64 + m]);
    acc = __fadd_rn(acc, upd);
  }
  {
    float ew  = __fmul_rn(dd, dd);
    float upd = __fmul_rn(ew, bases[(size_t)d * 64 + m]);
    acc = __fadd_rn(acc, upd);
  }
  aggl[w][m] = acc;
  if (m < 32) combl[w][m] = comb[(size_t)d * 32 + m];
  __syncthreads();
  #pragma unroll
  for (int half = 0; half < 2; ++half) {
    int j = m + half * 64;
    int h = j >> 4, f = j & 15;
    float cv = 0.f;
    #pragma unroll
    for (int b = 0; b < 4; ++b)
      cv = __fadd_rn(cv, __fmul_rn(combl[w][h * 4 + b], aggl[w][b * 16 + f]));
    cv = __fadd_rn(cv, convB[j]);
    int idx = d * 128 + j;
    float cm = c1_mem[idx], cs = c1_spk[idx];
    float nm = __fadd_rn(__fmul_rn(__fmul_rn(cm, 0.2f), __fsub_rn(1.f, cs)), cv);
    c1_mem[idx] = nm;
    c1_spk[idx] = nm > 0.5f ? 1.f : 0.f;
  }
}

// one BLAS panel of the gates GEMM: part[z] = A[:, panel_z] @ B[panel_z, :]
// 512 threads, 128x128 tile, 8x4 frag + double-buffered LDS (R6: 113us, 36 VGPR).
__global__ __launch_bounds__(512) void k_gpanel(
    const float* __restrict__ xl, const float* __restrict__ lh,
    const float* __restrict__ Wih, const float* __restrict__ Whh,
    float* __restrict__ part) {
  __shared__ __align__(16) float Ast[2][16][132];   // [buf][k][m] transposed
  __shared__ __align__(16) float Bs[2][16][132];    // [buf][k][n]
  const int tid = threadIdx.x;
  const int tx = tid & 31;              // output cols tx*4..tx*4+3
  const int ty = tid >> 5;              // output rows ty*8..ty*8+7
  const int n0 = blockIdx.x * 128;
  const int m0 = blockIdx.y * 128;
  const int z  = blockIdx.z;

  const float* Asrc; const float* Bsrc; int lda, k0, klen;
  if (z < 22) { Asrc = xl; Bsrc = Wih; lda = 8192; k0 = z * 384; klen = (z == 21) ? 128 : 384; }
  else        { Asrc = lh; Bsrc = Whh; lda = 512;  k0 = (z == 22) ? 0 : 384; klen = (z == 22) ? 384 : 128; }

  float acc[8][4];
  #pragma unroll
  for (int i = 0; i < 8; ++i)
    #pragma unroll
    for (int j = 0; j < 4; ++j) acc[i][j] = 0.f;

  const int arow = tid >> 2;            // 0..127
  const int acol = (tid & 3) * 4;       // 0,4,8,12
  const int brow = tid >> 5;            // 0..15
  const int bcol = (tid & 31) * 4;      // 0..124

  const int nkt = klen >> 4;

  float4 va, vb;                        // 8 staging VGPRs

  // prologue: tile 0 -> buf 0
  va = *(const float4*)(Asrc + (size_t)(m0 + arow) * lda + k0 + acol);
  vb = *(const float4*)(Bsrc + (size_t)(k0 + brow) * 2048 + n0 + bcol);
  Ast[0][acol + 0][arow] = va.x; Ast[0][acol + 1][arow] = va.y;
  Ast[0][acol + 2][arow] = va.z; Ast[0][acol + 3][arow] = va.w;
  *(float4*)&Bs[0][brow][bcol] = vb;
  __syncthreads();

  for (int kt = 0; kt < nkt; ++kt) {
    const int cur = kt & 1;
    const bool more = (kt + 1 < nkt);
    if (more) {   // issue next-tile loads; latency hides under compute
      const int kb = k0 + ((kt + 1) << 4);
      va = *(const float4*)(Asrc + (size_t)(m0 + arow) * lda + kb + acol);
      vb = *(const float4*)(Bsrc + (size_t)(kb + brow) * 2048 + n0 + bcol);
    }
    #pragma unroll
    for (int kk = 0; kk < 16; ++kk) {
      const float4 a0 = *(const float4*)&Ast[cur][kk][ty * 8];
      const float4 a1 = *(const float4*)&Ast[cur][kk][ty * 8 + 4];
      const float4 b0 = *(const float4*)&Bs[cur][kk][tx * 4];
      const float av[8] = {a0.x, a0.y, a0.z, a0.w, a1.x, a1.y, a1.z, a1.w};
      const float bv[4] = {b0.x, b0.y, b0.z, b0.w};
      #pragma unroll
      for (int i = 0; i < 8; ++i)
        #pragma unroll
        for (int j = 0; j < 4; ++j)
          acc[i][j] = __fmaf_rn(av[i], bv[j], acc[i][j]);
    }
    if (more) {
      const int nxt = cur ^ 1;
      Ast[nxt][acol + 0][arow] = va.x; Ast[nxt][acol + 1][arow] = va.y;
      Ast[nxt][acol + 2][arow] = va.z; Ast[nxt][acol + 3][arow] = va.w;
      *(float4*)&Bs[nxt][brow][bcol] = vb;
      __syncthreads();
    }
  }

  float* dstz = part + (size_t)z * GSTRIDE + (size_t)m0 * 2048 + n0;
  #pragma unroll
  for (int i = 0; i < 8; ++i) {
    const int mr = ty * 8 + i;
    *(float4*)(dstz + (size_t)mr * 2048 + tx * 4) =
        make_float4(acc[i][0], acc[i][1], acc[i][2], acc[i][3]);
  }
}

// combine panel partials strictly left-to-right (matches verified "tih += accP" chain)
__global__ __launch_bounds__(256) void k_combine(
    const float* __restrict__ part, const float* __restrict__ bih,
    const float* __restrict__ bhh, float* __restrict__ gates) {
  const int idx = blockIdx.x * 256 + threadIdx.x;    // m*2048 + u
  const float* p = part + idx;
  float tih = p[0];
  #pragma unroll
  for (int zz = 1; zz < 22; ++zz) tih = __fadd_rn(tih, p[(size_t)zz * GSTRIDE]);
  const float thh = __fadd_rn(p[22u * GSTRIDE], p[23u * GSTRIDE]);
  const int u = idx & 2047;
  gates[idx] = __fadd_rn(__fadd_rn(__fadd_rn(tih, bih[u]), thh), bhh[u]);
}

// fused: gate spikes -> LSTM cell -> fc1 LIF -> fc2 LIF -> h2 accum. 512 threads:
// one hidden unit per thread for the gate/LSTM phase; fc1 split a0(q<384) on
// threads 0-255 parallel with a1(q>=384) on 256-511, joined by fadd(a0,a1) == ref.
__global__ __launch_bounds__(512) void k_cell(
    const float* __restrict__ gates,
    float* __restrict__ lc, float* __restrict__ lh,
    const float* __restrict__ fc1W, const float* __restrict__ fc1b,
    const float* __restrict__ fc2W, const float* __restrict__ fc2b,
    float* __restrict__ h1_mem, float* __restrict__ h1_spk,
    float* __restrict__ h2_mem, float* __restrict__ h2_spk, float* __restrict__ h2_sum) {
  __shared__ float lhl[512];
  __shared__ float a1buf[256];
  __shared__ float sp1l[256];
  const int s = blockIdx.x;
  const int tid = threadIdx.x;
  {
    const int h = tid;
    const float giv = gates[(size_t)s * 2048 + h];
    const float gfv = gates[(size_t)s * 2048 + 512 + h];
    const float ggv = gates[(size_t)s * 2048 + 1024 + h];
    const float gov = gates[(size_t)s * 2048 + 1536 + h];
    const float iv = giv > 0.f ? 1.f : 0.f;
    const float fv = gfv > 0.f ? 1.f : 0.f;
    const float gv = ggv > 0.f ? 1.f : 0.f;
    const float ov = gov > 0.f ? 1.f : 0.f;
    const int li = s * 512 + h;
    const float lcv = __fadd_rn(__fmul_rn(fv, lc[li]), __fmul_rn(iv, gv));
    lc[li] = lcv;
    const float lhv = __fmul_rn(lcv, ov);
    lh[li] = lhv;
    lhl[h] = lhv;
  }
  __syncthreads();
  float a0 = 0.f;
  if (tid < 256) {
    const int p = tid;
    #pragma unroll 8
    for (int q = 0; q < 384; ++q) a0 = __fmaf_rn(lhl[q], fc1W[q * 256 + p], a0);
  } else {
    const int p = tid - 256;
    float a1 = 0.f;
    #pragma unroll 8
    for (int q = 384; q < 512; ++q) a1 = __fmaf_rn(lhl[q], fc1W[q * 256 + p], a1);
    a1buf[p] = a1;
  }
  __syncthreads();
  if (tid < 256) {
    const int p = tid;
    const float dot1 = __fadd_rn(a0, a1buf[p]);
    const int i1 = s * 256 + p;
    const float m1 = h1_mem[i1], s1o = h1_spk[i1];
    const float nm1 = __fadd_rn(__fadd_rn(__fmul_rn(__fmul_rn(m1, 0.2f), __fsub_rn(1.f, s1o)), dot1), fc1b[p]);
    h1_mem[i1] = nm1;
    const float sp1 = nm1 > 0.5f ? 1.f : 0.f;
    h1_spk[i1] = sp1;
    sp1l[p] = sp1;
  }
  __syncthreads();
  if (tid < 4) {
    const int p = tid;
    float acc = 0.f;
    for (int q = 0; q < 256; ++q) acc = __fmaf_rn(sp1l[q], fc2W[q * 4 + p], acc);
    const int i2 = s * 4 + p;
    const float m2 = h2_mem[i2], s2o = h2_spk[i2];
    const float nm2 = __fadd_rn(__fadd_rn(__fmul_rn(__fmul_rn(m2, 0.2f), __fsub_rn(1.f, s2o)), acc), fc2b[p]);
    h2_mem[i2] = nm2;
    const float sp2 = nm2 > 0.5f ? 1.f : 0.f;
    h2_spk[i2] = sp2;
    h2_sum[i2] = __fadd_rn(h2_sum[i2], sp2);
  }
}

__global__ void k_out(const float* __restrict__ h2_sum, float* __restrict__ out) {
  int i = blockIdx.x * 256 + threadIdx.x;
  if (i < SG * 4) out[i] = __fmul_rn(h2_sum[i], 0.03125f);
}

// ---------------- launch ----------------
extern "C" void kernel_launch(void* const* d_in, const int* in_sizes, int n_in,
                              void* d_out, int out_size, void* d_ws, size_t ws_size,
                              hipStream_t stream) {
  const float* x      = (const float*)d_in[0];
  const int*   ei     = (const int*)  d_in[1];
  const float* encW   = (const float*)d_in[2];
  const float* encB   = (const float*)d_in[3];
  const float* basesW = (const float*)d_in[4];
  const float* basesB = (const float*)d_in[5];
  const float* combW  = (const float*)d_in[6];
  const float* combB  = (const float*)d_in[7];
  const float* convB  = (const float*)d_in[8];
  const float* Wih    = (const float*)d_in[9];
  const float* Whh    = (const float*)d_in[10];
  const float* bih    = (const float*)d_in[11];
  const float* bhh    = (const float*)d_in[12];
  const float* fc1W   = (const float*)d_in[13];
  const float* fc1b   = (const float*)d_in[14];
  const float* fc2W   = (const float*)d_in[15];
  const float* fc2b   = (const float*)d_in[16];

  float* ws = (float*)d_ws;
  float* enc_mem = ws + OFF_ENC_MEM;
  float* enc_spk = ws + OFF_ENC_SPK;
  float* c1_mem  = ws + OFF_C1_MEM;
  float* c1_spk  = ws + OFF_C1_SPK;   // xl
  float* lhp     = ws + OFF_LH;
  float* lcp     = ws + OFF_LC;
  float* h1_mem  = ws + OFF_H1_MEM;
  float* h1_spk  = ws + OFF_H1_SPK;
  float* h2_mem  = ws + OFF_H2_MEM;
  float* h2_spk  = ws + OFF_H2_SPK;
  float* h2_sum  = ws + OFF_H2_SUM;
  float* bases   = ws + OFF_BASES;
  float* comb    = ws + OFF_COMB;
  float* gates   = ws + OFF_GATES;
  float* partp   = ws + OFF_PART;
  float* dinv    = ws + OFF_DINV;
  float* colw    = ws + OFF_COLW;
  int* ibase = (int*)((char*)d_ws + (size_t)FLOAT_END * 4);
  int* deg  = ibase + IOFF_DEG;
  int* fill = ibase + IOFF_FILL;
  int* rowp = ibase + IOFF_ROWPTR;
  int* eid  = ibase + IOFF_EID;
  int* col  = ibase + IOFF_COL;

  hipMemsetAsync(ws, 0, (size_t)ZERO_FLOATS * 4, stream);
  hipMemsetAsync(ibase, 0, 32768 * 4, stream);

  k_deg    <<<NE / 256, 256, 0, stream>>>(ei, deg);
  k_dinv   <<<NN / 256, 256, 0, stream>>>(deg, dinv);
  k_scan   <<<1, 1024, 0, stream>>>(deg, rowp);
  k_scatter<<<NE / 256, 256, 0, stream>>>(ei, rowp, fill, eid);
  k_sortadj<<<NN / 256, 256, 0, stream>>>(rowp, eid, ei, dinv, col, colw);

  for (int t = 0; t < TSTEPS; ++t) {
    k_bases_comb<<<NN / 64, 512, 0, stream>>>(x, encW, encB, enc_mem, enc_spk,
                                              basesW, basesB, combW, combB, bases, comb, t);
    k_aggconv   <<<NN / 4, 256, 0, stream>>>(bases, comb, dinv, rowp, col, colw, convB, c1_mem, c1_spk);
    k_gpanel    <<<dim3(16, 2, NPANEL), 512, 0, stream>>>(c1_spk, lhp, Wih, Whh, partp);
    k_combine   <<<2048, 256, 0, stream>>>(partp, bih, bhh, gates);
    k_cell      <<<SG, 512, 0, stream>>>(gates, lcp, lhp, fc1W, fc1b, fc2W, fc2b,
                                         h1_mem, h1_spk, h2_mem, h2_spk, h2_sum);
  }
  k_out<<<4, 256, 0, stream>>>(h2_sum, (float*)d_out);
}